// Round 1
// baseline (494.823 us; speedup 1.0000x reference)
//
#include <hip/hip_runtime.h>

// ---------------------------------------------------------------------------
// TransformerBlock (B=2, T=2048, D=1024, H=16, DH=64, DFF=4096) on gfx950.
// Strategy: bf16 MFMA (16x16x32) for all GEMMs + flash attention.
// bf16-level tolerance is allowed by the harness (threshold ~0.119).
// ---------------------------------------------------------------------------

#define B_   2
#define T_   2048
#define D_   1024
#define H_   16
#define DH_  64
#define DFF_ 4096
#define M_   4096   // B_*T_

typedef __attribute__((ext_vector_type(8))) short short8;   // 8 x bf16 (4 VGPRs)
typedef __attribute__((ext_vector_type(4))) float f32x4;    // MFMA accumulator

__device__ __forceinline__ unsigned short f2bf(float f) {
    union { float f; unsigned int u; } x; x.f = f;
    return (unsigned short)((x.u + 0x7FFFu + ((x.u >> 16) & 1u)) >> 16); // RNE
}

// ---------------------------------------------------------------------------
// LayerNorm: fp32 row (D=1024) -> bf16 row.  Matches (x-mean)/(std+eps)*s+b.
// One block (256 thr) per row; float4 loads; wave + LDS reduction.
// ---------------------------------------------------------------------------
__global__ __launch_bounds__(256) void ln_kernel(
    const float* __restrict__ in, const float* __restrict__ sc,
    const float* __restrict__ bi, unsigned short* __restrict__ out)
{
    __shared__ float ls[4], lq[4];
    const int row = blockIdx.x, t = threadIdx.x;
    const float* rp = in + (size_t)row * D_;
    float4 v = *reinterpret_cast<const float4*>(rp + t * 4);
    float s  = v.x + v.y + v.z + v.w;
    float sq = v.x * v.x + v.y * v.y + v.z * v.z + v.w * v.w;
#pragma unroll
    for (int d = 32; d > 0; d >>= 1) {
        s  += __shfl_down(s, d);
        sq += __shfl_down(sq, d);
    }
    if ((t & 63) == 0) { ls[t >> 6] = s; lq[t >> 6] = sq; }
    __syncthreads();
    s  = ls[0] + ls[1] + ls[2] + ls[3];
    sq = lq[0] + lq[1] + lq[2] + lq[3];
    float mean = s * (1.f / D_);
    float var  = fmaxf(sq * (1.f / D_) - mean * mean, 0.f);
    float inv  = 1.f / (sqrtf(var) + 1e-5f);
    float4 scv = *reinterpret_cast<const float4*>(sc + t * 4);
    float4 biv = *reinterpret_cast<const float4*>(bi + t * 4);
    ushort4 ov;
    ov.x = f2bf((v.x - mean) * inv * scv.x + biv.x);
    ov.y = f2bf((v.y - mean) * inv * scv.y + biv.y);
    ov.z = f2bf((v.z - mean) * inv * scv.z + biv.z);
    ov.w = f2bf((v.w - mean) * inv * scv.w + biv.w);
    *reinterpret_cast<ushort4*>(out + (size_t)row * D_ + t * 4) = ov;
}

// ---------------------------------------------------------------------------
// Convert fp32 [R][C] -> bf16 transposed [C][R], optional scale.
// 64x64 LDS tile transpose; coalesced read & write.
// ---------------------------------------------------------------------------
__global__ __launch_bounds__(256) void cvt_t_kernel(
    const float* __restrict__ in, unsigned short* __restrict__ out,
    int R, int C, float scale)
{
    __shared__ unsigned short lds[64][66];
    const int r0 = blockIdx.x * 64, c0 = blockIdx.y * 64;
#pragma unroll
    for (int i = 0; i < 16; i++) {
        int idx = threadIdx.x + i * 256;
        int r = idx >> 6, c = idx & 63;
        lds[r][c] = f2bf(in[(size_t)(r0 + r) * C + (c0 + c)] * scale);
    }
    __syncthreads();
#pragma unroll
    for (int i = 0; i < 16; i++) {
        int idx = threadIdx.x + i * 256;
        int r = idx >> 6, c = idx & 63;
        out[(size_t)(c0 + r) * R + (r0 + c)] = lds[c][r];
    }
}

// ---------------------------------------------------------------------------
// GEMM C[M,N] = A[M,K] * B^T[N,K]  (both bf16, row-major-by-K, "NT")
// 128x128 block tile, BK=32, 4 waves (2x2), each wave 64x64 via 4x4 MFMA frags.
// LDS rows padded to 40 bf16 (80 B) -> 2-way bank aliasing only (free).
// Epilogues:
//   EPI_QKV3     : N=3072 fused QKV. Q,K scatter to (B,H,T,DH); V to (B,H,DH,T).
//   EPI_BIAS_RES : += bias[col] + resid[row,col]; fp32 out.
//   EPI_BIAS_GELU: += bias[col]; exact GELU; bf16 out.
// ---------------------------------------------------------------------------
enum { EPI_QKV3 = 0, EPI_BIAS_RES = 1, EPI_BIAS_GELU = 2 };

template <int EPI, int KDIM, int NDIM>
__global__ __launch_bounds__(256) void gemm_nt(
    const unsigned short* __restrict__ A,
    const unsigned short* __restrict__ Bt,
    unsigned short* __restrict__ out0,
    unsigned short* __restrict__ out1,
    unsigned short* __restrict__ out2,
    float* __restrict__ outF,
    const float* __restrict__ bias,
    const float* __restrict__ resid)
{
    __shared__ __align__(16) unsigned short sA[128][40];
    __shared__ __align__(16) unsigned short sB[128][40];
    const int tid = threadIdx.x, lane = tid & 63, w = tid >> 6;
    const int bm = blockIdx.x * 128, bn = blockIdx.y * 128;
    const int wm = (w >> 1) * 64, wn = (w & 1) * 64;
    const int rsel = lane & 15, koff = (lane >> 4) * 8;

    f32x4 acc[4][4];
#pragma unroll
    for (int m = 0; m < 4; m++)
#pragma unroll
        for (int n = 0; n < 4; n++) acc[m][n] = (f32x4){0.f, 0.f, 0.f, 0.f};

    for (int k0 = 0; k0 < KDIM; k0 += 32) {
        __syncthreads();   // previous iter's fragment reads must finish
#pragma unroll
        for (int i = 0; i < 2; i++) {
            int slot = tid + i * 256;          // 0..511
            int row = slot >> 2, seg = slot & 3;
            *reinterpret_cast<uint4*>(&sA[row][seg * 8]) =
                *reinterpret_cast<const uint4*>(&A[(size_t)(bm + row) * KDIM + k0 + seg * 8]);
            *reinterpret_cast<uint4*>(&sB[row][seg * 8]) =
                *reinterpret_cast<const uint4*>(&Bt[(size_t)(bn + row) * KDIM + k0 + seg * 8]);
        }
        __syncthreads();
        short8 a[4], b[4];
#pragma unroll
        for (int m = 0; m < 4; m++)
            a[m] = *reinterpret_cast<const short8*>(&sA[wm + m * 16 + rsel][koff]);
#pragma unroll
        for (int n = 0; n < 4; n++)
            b[n] = *reinterpret_cast<const short8*>(&sB[wn + n * 16 + rsel][koff]);
#pragma unroll
        for (int m = 0; m < 4; m++)
#pragma unroll
            for (int n = 0; n < 4; n++)
                acc[m][n] = __builtin_amdgcn_mfma_f32_16x16x32_bf16(a[m], b[n], acc[m][n], 0, 0, 0);
    }

    const int rq = (lane >> 4) * 4;
#pragma unroll
    for (int m = 0; m < 4; m++)
#pragma unroll
        for (int n = 0; n < 4; n++)
#pragma unroll
            for (int j = 0; j < 4; j++) {
                int rg = bm + wm + m * 16 + rq + j;   // global row (B*T)
                int cg = bn + wn + n * 16 + rsel;     // global col
                float v = acc[m][n][j];
                if constexpr (EPI == EPI_QKV3) {
                    int which = cg >> 10, col = cg & 1023;
                    int h = col >> 6, dh = col & 63;
                    int bb = rg >> 11, t = rg & 2047;
                    if (which == 0)
                        out0[(((size_t)(bb * H_ + h)) * T_ + t) * DH_ + dh] = f2bf(v);
                    else if (which == 1)
                        out1[(((size_t)(bb * H_ + h)) * T_ + t) * DH_ + dh] = f2bf(v);
                    else
                        out2[(((size_t)(bb * H_ + h)) * DH_ + dh) * T_ + t] = f2bf(v);
                } else if constexpr (EPI == EPI_BIAS_RES) {
                    v += bias[cg] + resid[(size_t)rg * NDIM + cg];
                    outF[(size_t)rg * NDIM + cg] = v;
                } else {
                    v += bias[cg];
                    v = 0.5f * v * (1.0f + erff(v * 0.70710678118654752f));
                    out0[(size_t)rg * NDIM + cg] = f2bf(v);
                }
            }
}

// ---------------------------------------------------------------------------
// Causal flash attention, bf16 MFMA.
// Q (B,H,T,DH) pre-scaled by 1/sqrt(DH) (folded into wq); K (B,H,T,DH);
// V stored transposed (B,H,DH,T); O written as (B,T,D).
// Block = 4 waves; each wave owns 16 q-rows; KV tiles of 32.
// Online softmax kept per-lane for the lane's 4 S-rows; P transposed to
// A-fragment layout via a per-wave LDS bounce (no cross-wave sync needed).
// ---------------------------------------------------------------------------
__global__ __launch_bounds__(256) void attn_kernel(
    const unsigned short* __restrict__ q,
    const unsigned short* __restrict__ k,
    const unsigned short* __restrict__ vt,
    unsigned short* __restrict__ o)
{
    __shared__ __align__(16) unsigned short p_lds[4][16][40];
    const int tid = threadIdx.x, lane = tid & 63, w = tid >> 6;
    const int qt = blockIdx.x, bh = blockIdx.y;
    const int qbase = qt * 64 + w * 16;
    const unsigned short* qp = q  + (size_t)bh * T_ * DH_;
    const unsigned short* kp = k  + (size_t)bh * T_ * DH_;
    const unsigned short* vp = vt + (size_t)bh * DH_ * T_;
    const int rsel = lane & 15, koff = (lane >> 4) * 8, rq = (lane >> 4) * 4;

    short8 aq0 = *reinterpret_cast<const short8*>(&qp[(size_t)(qbase + rsel) * DH_ + koff]);
    short8 aq1 = *reinterpret_cast<const short8*>(&qp[(size_t)(qbase + rsel) * DH_ + 32 + koff]);

    float m_run[4], l_run[4];
    f32x4 oacc[4];
#pragma unroll
    for (int j = 0; j < 4; j++) { m_run[j] = -INFINITY; l_run[j] = 0.f; }
#pragma unroll
    for (int n = 0; n < 4; n++) oacc[n] = (f32x4){0.f, 0.f, 0.f, 0.f};

    const int kv_end = qbase + 16;   // causal: this wave needs kv < qbase+16
    for (int kv0 = 0; kv0 < kv_end; kv0 += 32) {
        f32x4 s[2];
#pragma unroll
        for (int sub = 0; sub < 2; sub++) {
            int colbase = kv0 + sub * 16 + rsel;
            short8 bk0 = *reinterpret_cast<const short8*>(&kp[(size_t)colbase * DH_ + koff]);
            short8 bk1 = *reinterpret_cast<const short8*>(&kp[(size_t)colbase * DH_ + 32 + koff]);
            f32x4 t = (f32x4){0.f, 0.f, 0.f, 0.f};
            t = __builtin_amdgcn_mfma_f32_16x16x32_bf16(aq0, bk0, t, 0, 0, 0);
            t = __builtin_amdgcn_mfma_f32_16x16x32_bf16(aq1, bk1, t, 0, 0, 0);
            s[sub] = t;
        }
        // causal mask (scores already scaled via wq)
#pragma unroll
        for (int sub = 0; sub < 2; sub++)
#pragma unroll
            for (int j = 0; j < 4; j++) {
                int rg = qbase + rq + j, cg = kv0 + sub * 16 + rsel;
                if (cg > rg) s[sub][j] = -INFINITY;
            }
        // row max across the 16-lane col group
        float mx[4];
#pragma unroll
        for (int j = 0; j < 4; j++) mx[j] = fmaxf(s[0][j], s[1][j]);
#pragma unroll
        for (int d = 1; d < 16; d <<= 1)
#pragma unroll
            for (int j = 0; j < 4; j++) mx[j] = fmaxf(mx[j], __shfl_xor(mx[j], d));
        float al[4];
#pragma unroll
        for (int j = 0; j < 4; j++) {
            float mn = fmaxf(m_run[j], mx[j]);
            al[j] = __expf(m_run[j] - mn);   // exp(-inf)=0 on first tile
            m_run[j] = mn;
            l_run[j] *= al[j];
        }
#pragma unroll
        for (int sub = 0; sub < 2; sub++)
#pragma unroll
            for (int j = 0; j < 4; j++) {
                float p = __expf(s[sub][j] - m_run[j]);
                l_run[j] += p;               // per-lane partial row sum
                p_lds[w][rq + j][sub * 16 + rsel] = f2bf(p);
            }
#pragma unroll
        for (int n = 0; n < 4; n++)
#pragma unroll
            for (int j = 0; j < 4; j++) oacc[n][j] *= al[j];
        // read P back in A-fragment layout (same wave; DS pipe is in-order)
        short8 ap = *reinterpret_cast<const short8*>(&p_lds[w][rsel][koff]);
#pragma unroll
        for (int n = 0; n < 4; n++) {
            short8 bv = *reinterpret_cast<const short8*>(
                &vp[(size_t)(n * 16 + rsel) * T_ + kv0 + koff]);
            oacc[n] = __builtin_amdgcn_mfma_f32_16x16x32_bf16(ap, bv, oacc[n], 0, 0, 0);
        }
    }
    // finish row sums across the 16-lane group
#pragma unroll
    for (int d = 1; d < 16; d <<= 1)
#pragma unroll
        for (int j = 0; j < 4; j++) l_run[j] += __shfl_xor(l_run[j], d);

    const int bb = bh >> 4, h = bh & 15;
#pragma unroll
    for (int j = 0; j < 4; j++) {
        float inv = 1.0f / l_run[j];
        int rg = qbase + rq + j;
#pragma unroll
        for (int n = 0; n < 4; n++)
            o[((size_t)(bb * T_ + rg)) * D_ + h * DH_ + n * 16 + rsel] =
                f2bf(oacc[n][j] * inv);
    }
}

// ---------------------------------------------------------------------------
// Launch: converts -> LN1 -> QKV -> attn -> WO(+res) -> LN2 -> FF1(GELU) -> FF2(+res)
// ---------------------------------------------------------------------------
extern "C" void kernel_launch(void* const* d_in, const int* in_sizes, int n_in,
                              void* d_out, int out_size, void* d_ws, size_t ws_size,
                              hipStream_t stream)
{
    const float* x    = (const float*)d_in[0];
    const float* wq   = (const float*)d_in[1];
    const float* wk   = (const float*)d_in[2];
    const float* wv   = (const float*)d_in[3];
    const float* wo   = (const float*)d_in[4];
    const float* bo   = (const float*)d_in[5];
    const float* w1   = (const float*)d_in[6];
    const float* b1   = (const float*)d_in[7];
    const float* w2   = (const float*)d_in[8];
    const float* b2   = (const float*)d_in[9];
    const float* ln1s = (const float*)d_in[10];
    const float* ln1b = (const float*)d_in[11];
    const float* ln2s = (const float*)d_in[12];
    const float* ln2b = (const float*)d_in[13];
    float* out = (float*)d_out;

    // workspace layout (bf16 buffers, all 16B-aligned); total ~62 MB
    char* ws = (char*)d_ws;
    unsigned short* wqkv_t = (unsigned short*)ws;                     // [3072][1024]
    unsigned short* wo_t   = wqkv_t + (size_t)3072 * 1024;            // [1024][1024]
    unsigned short* w1_t   = wo_t   + (size_t)1024 * 1024;            // [4096][1024]
    unsigned short* w2_t   = w1_t   + (size_t)4096 * 1024;            // [1024][4096]
    unsigned short* hbuf   = w2_t   + (size_t)1024 * 4096;            // [4096][1024] (h, then h2)
    unsigned short* qb     = hbuf   + (size_t)4096 * 1024;            // (B,H,T,DH)
    unsigned short* kb     = qb     + (size_t)32 * 2048 * 64;         // (B,H,T,DH)
    unsigned short* vtb    = kb     + (size_t)32 * 2048 * 64;         // (B,H,DH,T)
    unsigned short* ao     = vtb    + (size_t)32 * 64 * 2048;         // (B,T,D)
    unsigned short* f1     = qb;  // reuse q|k|vt|ao span (32 MB) after attention+WO

    // weight conversions (wq folded with 1/sqrt(DH) = 0.125)
    cvt_t_kernel<<<dim3(16, 16), 256, 0, stream>>>(wq, wqkv_t,                  1024, 1024, 0.125f);
    cvt_t_kernel<<<dim3(16, 16), 256, 0, stream>>>(wk, wqkv_t + 1024 * 1024,    1024, 1024, 1.f);
    cvt_t_kernel<<<dim3(16, 16), 256, 0, stream>>>(wv, wqkv_t + 2 * 1024 * 1024,1024, 1024, 1.f);
    cvt_t_kernel<<<dim3(16, 16), 256, 0, stream>>>(wo, wo_t, 1024, 1024, 1.f);
    cvt_t_kernel<<<dim3(16, 64), 256, 0, stream>>>(w1, w1_t, 1024, 4096, 1.f);
    cvt_t_kernel<<<dim3(64, 16), 256, 0, stream>>>(w2, w2_t, 4096, 1024, 1.f);

    // attention sublayer
    ln_kernel<<<M_, 256, 0, stream>>>(x, ln1s, ln1b, hbuf);
    gemm_nt<EPI_QKV3, 1024, 3072><<<dim3(32, 24), 256, 0, stream>>>(
        hbuf, wqkv_t, qb, kb, vtb, nullptr, nullptr, nullptr);
    attn_kernel<<<dim3(32, 32), 256, 0, stream>>>(qb, kb, vtb, ao);
    gemm_nt<EPI_BIAS_RES, 1024, 1024><<<dim3(32, 8), 256, 0, stream>>>(
        ao, wo_t, nullptr, nullptr, nullptr, out, bo, x);   // out = x2

    // feed-forward sublayer
    ln_kernel<<<M_, 256, 0, stream>>>(out, ln2s, ln2b, hbuf);
    gemm_nt<EPI_BIAS_GELU, 1024, 4096><<<dim3(32, 32), 256, 0, stream>>>(
        hbuf, w1_t, f1, nullptr, nullptr, nullptr, b1, nullptr);
    gemm_nt<EPI_BIAS_RES, 4096, 1024><<<dim3(32, 8), 256, 0, stream>>>(
        f1, w2_t, nullptr, nullptr, nullptr, out, b2, out); // out = x2 + ff
}

// Round 2
// 359.228 us; speedup vs baseline: 1.3775x; 1.3775x over previous
//
#include <hip/hip_runtime.h>

// ---------------------------------------------------------------------------
// TransformerBlock (B=2, T=2048, D=1024, H=16, DH=64, DFF=4096) on gfx950.
// bf16 MFMA (16x16x32) GEMMs + LDS-staged flash attention.
// Round 2: global_load_lds(16B) + XOR-swizzled LDS for GEMM (m97 ladder) and
// attention (KVBLK=64, 32 q-rows/wave, 2-phase double buffer, exp2 softmax).
// ---------------------------------------------------------------------------

#define B_   2
#define T_   2048
#define D_   1024
#define H_   16
#define DH_  64
#define DFF_ 4096
#define M_   4096   // B_*T_

typedef __attribute__((ext_vector_type(8))) short short8;   // 8 x bf16
typedef __attribute__((ext_vector_type(4))) float f32x4;    // MFMA accumulator

__device__ __forceinline__ unsigned short f2bf(float f) {
    union { float f; unsigned int u; } x; x.f = f;
    return (unsigned short)((x.u + 0x7FFFu + ((x.u >> 16) & 1u)) >> 16); // RNE
}

// global -> LDS direct copy, 16 B per lane. lds base must be wave-uniform;
// lane i's data lands at base + i*16.
__device__ __forceinline__ void gload_lds16(const unsigned short* g, unsigned short* l) {
    __builtin_amdgcn_global_load_lds(
        (const __attribute__((address_space(1))) void*)g,
        (__attribute__((address_space(3))) void*)l, 16, 0, 0);
}

// Swizzled fragment pointer into a [rows][64] bf16 tile (128 B rows).
// Storage swizzle: byte = row*128 + (chunk ^ (row&7))*16  (chunk = 16B unit).
__device__ __forceinline__ const short8* swz_frag(const unsigned short* base, int row, int ks, int g) {
    int byte = row * 128 + ((ks * 64 + g * 16) ^ ((row & 7) << 4));
    return reinterpret_cast<const short8*>(reinterpret_cast<const char*>(base) + byte);
}

// ---------------------------------------------------------------------------
// LayerNorm: fp32 row (D=1024) -> bf16 row.
// ---------------------------------------------------------------------------
__global__ __launch_bounds__(256) void ln_kernel(
    const float* __restrict__ in, const float* __restrict__ sc,
    const float* __restrict__ bi, unsigned short* __restrict__ out)
{
    __shared__ float ls[4], lq[4];
    const int row = blockIdx.x, t = threadIdx.x;
    const float* rp = in + (size_t)row * D_;
    float4 v = *reinterpret_cast<const float4*>(rp + t * 4);
    float s  = v.x + v.y + v.z + v.w;
    float sq = v.x * v.x + v.y * v.y + v.z * v.z + v.w * v.w;
#pragma unroll
    for (int d = 32; d > 0; d >>= 1) {
        s  += __shfl_down(s, d);
        sq += __shfl_down(sq, d);
    }
    if ((t & 63) == 0) { ls[t >> 6] = s; lq[t >> 6] = sq; }
    __syncthreads();
    s  = ls[0] + ls[1] + ls[2] + ls[3];
    sq = lq[0] + lq[1] + lq[2] + lq[3];
    float mean = s * (1.f / D_);
    float var  = fmaxf(sq * (1.f / D_) - mean * mean, 0.f);
    float inv  = 1.f / (sqrtf(var) + 1e-5f);
    float4 scv = *reinterpret_cast<const float4*>(sc + t * 4);
    float4 biv = *reinterpret_cast<const float4*>(bi + t * 4);
    ushort4 ov;
    ov.x = f2bf((v.x - mean) * inv * scv.x + biv.x);
    ov.y = f2bf((v.y - mean) * inv * scv.y + biv.y);
    ov.z = f2bf((v.z - mean) * inv * scv.z + biv.z);
    ov.w = f2bf((v.w - mean) * inv * scv.w + biv.w);
    *reinterpret_cast<ushort4*>(out + (size_t)row * D_ + t * 4) = ov;
}

// ---------------------------------------------------------------------------
// Convert fp32 [R][C] -> bf16 transposed [C][R], optional scale.
// ---------------------------------------------------------------------------
__global__ __launch_bounds__(256) void cvt_t_kernel(
    const float* __restrict__ in, unsigned short* __restrict__ out,
    int R, int C, float scale)
{
    __shared__ unsigned short lds[64][66];
    const int r0 = blockIdx.x * 64, c0 = blockIdx.y * 64;
#pragma unroll
    for (int i = 0; i < 16; i++) {
        int idx = threadIdx.x + i * 256;
        int r = idx >> 6, c = idx & 63;
        lds[r][c] = f2bf(in[(size_t)(r0 + r) * C + (c0 + c)] * scale);
    }
    __syncthreads();
#pragma unroll
    for (int i = 0; i < 16; i++) {
        int idx = threadIdx.x + i * 256;
        int r = idx >> 6, c = idx & 63;
        out[(size_t)(c0 + r) * R + (r0 + c)] = lds[c][r];
    }
}

// ---------------------------------------------------------------------------
// GEMM C[M,N] = A[M,K] * B^T[N,K]  (bf16 "NT"), 128x128 tile, BK=64, 4 waves.
// Staging: global_load_lds dwordx4 into XOR-swizzled linear LDS (m97 ladder).
// ---------------------------------------------------------------------------
enum { EPI_QKV3 = 0, EPI_BIAS_RES = 1, EPI_BIAS_GELU = 2 };

template <int EPI, int KDIM, int NDIM>
__global__ __launch_bounds__(256) void gemm_nt(
    const unsigned short* __restrict__ A,
    const unsigned short* __restrict__ Bt,
    unsigned short* __restrict__ out0,
    unsigned short* __restrict__ out1,
    unsigned short* __restrict__ out2,
    float* __restrict__ outF,
    const float* __restrict__ bias,
    const float* __restrict__ resid)
{
    __shared__ __align__(16) unsigned short sA[128 * 64];   // 16 KB, swizzled
    __shared__ __align__(16) unsigned short sB[128 * 64];
    const int tid = threadIdx.x, lane = tid & 63, w = tid >> 6;
    const int bm = blockIdx.x * 128, bn = blockIdx.y * 128;
    const int wm = (w >> 1) * 64, wn = (w & 1) * 64;
    const int rsel = lane & 15, g = lane >> 4;
    const int slot0 = w * 64 + lane;

    f32x4 acc[4][4];
#pragma unroll
    for (int m = 0; m < 4; m++)
#pragma unroll
        for (int n = 0; n < 4; n++) acc[m][n] = (f32x4){0.f, 0.f, 0.f, 0.f};

    for (int k0 = 0; k0 < KDIM; k0 += 64) {
        __syncthreads();   // all waves done reading previous tile
#pragma unroll
        for (int i = 0; i < 4; i++) {
            int slot = i * 256 + slot0;          // 0..1023
            int row = slot >> 3, ch = slot & 7;
            int sc = ch ^ (row & 7);             // inverse-swizzled source chunk
            gload_lds16(&A [(size_t)(bm + row) * KDIM + k0 + sc * 8], &sA[(i * 256 + w * 64) * 8]);
            gload_lds16(&Bt[(size_t)(bn + row) * KDIM + k0 + sc * 8], &sB[(i * 256 + w * 64) * 8]);
        }
        __syncthreads();   // drains vmcnt -> tile resident
#pragma unroll
        for (int ks = 0; ks < 2; ks++) {
            short8 a[4], b[4];
#pragma unroll
            for (int m = 0; m < 4; m++) a[m] = *swz_frag(sA, wm + m * 16 + rsel, ks, g);
#pragma unroll
            for (int n = 0; n < 4; n++) b[n] = *swz_frag(sB, wn + n * 16 + rsel, ks, g);
#pragma unroll
            for (int m = 0; m < 4; m++)
#pragma unroll
                for (int n = 0; n < 4; n++)
                    acc[m][n] = __builtin_amdgcn_mfma_f32_16x16x32_bf16(a[m], b[n], acc[m][n], 0, 0, 0);
        }
    }

    const int rq = g * 4;
#pragma unroll
    for (int m = 0; m < 4; m++)
#pragma unroll
        for (int n = 0; n < 4; n++)
#pragma unroll
            for (int j = 0; j < 4; j++) {
                int rg = bm + wm + m * 16 + rq + j;   // global row (B*T)
                int cg = bn + wn + n * 16 + rsel;     // global col
                float v = acc[m][n][j];
                if constexpr (EPI == EPI_QKV3) {
                    int which = cg >> 10, col = cg & 1023;
                    int h = col >> 6, dh = col & 63;
                    int bb = rg >> 11, t = rg & 2047;
                    if (which == 0)
                        out0[(((size_t)(bb * H_ + h)) * T_ + t) * DH_ + dh] = f2bf(v);
                    else if (which == 1)
                        out1[(((size_t)(bb * H_ + h)) * T_ + t) * DH_ + dh] = f2bf(v);
                    else
                        out2[(((size_t)(bb * H_ + h)) * DH_ + dh) * T_ + t] = f2bf(v);
                } else if constexpr (EPI == EPI_BIAS_RES) {
                    v += bias[cg] + resid[(size_t)rg * NDIM + cg];
                    outF[(size_t)rg * NDIM + cg] = v;
                } else {
                    v += bias[cg];
                    v = 0.5f * v * (1.0f + erff(v * 0.70710678118654752f));
                    out0[(size_t)rg * NDIM + cg] = f2bf(v);
                }
            }
}

// ---------------------------------------------------------------------------
// Causal flash attention, bf16 MFMA, LDS-staged K/V (KVBLK=64, double buffer).
// Q (B,H,T,DH) pre-scaled by 0.125*log2(e) (folded into wq); softmax in
// log2 domain (exp2). V stored transposed (B,H,DH,T). O written as (B,T,D).
// Block = 4 waves; wave owns 32 q-rows (2 m-frags); grid (T/128, B*H).
// ---------------------------------------------------------------------------
__global__ __launch_bounds__(256) void attn_kernel(
    const unsigned short* __restrict__ q,
    const unsigned short* __restrict__ k,
    const unsigned short* __restrict__ vt,
    unsigned short* __restrict__ o)
{
    __shared__ __align__(16) unsigned short sK[2][64 * 64];   // 8 KB each, swizzled
    __shared__ __align__(16) unsigned short sV[2][64 * 64];
    __shared__ __align__(16) unsigned short pl[4][32][72];    // per-wave P bounce
    const int tid = threadIdx.x, lane = tid & 63, w = tid >> 6;
    const int qt = blockIdx.x, bh = blockIdx.y;
    const int qbase = qt * 128 + w * 32;
    const unsigned short* qp = q  + (size_t)bh * T_ * DH_;
    const unsigned short* kp = k  + (size_t)bh * T_ * DH_;
    const unsigned short* vp = vt + (size_t)bh * DH_ * T_;
    const int rsel = lane & 15, g = lane >> 4, koff = g * 8, rq = g * 4;
    const int slot0 = w * 64 + lane;

    short8 aq[2][2];
#pragma unroll
    for (int m = 0; m < 2; m++)
#pragma unroll
        for (int ks = 0; ks < 2; ks++)
            aq[m][ks] = *reinterpret_cast<const short8*>(
                &qp[(size_t)(qbase + m * 16 + rsel) * DH_ + ks * 32 + koff]);

    float mr[2][4], lr[2][4];
    f32x4 oacc[2][4];
#pragma unroll
    for (int m = 0; m < 2; m++)
#pragma unroll
        for (int j = 0; j < 4; j++) { mr[m][j] = -INFINITY; lr[m][j] = 0.f; }
#pragma unroll
    for (int m = 0; m < 2; m++)
#pragma unroll
        for (int n = 0; n < 4; n++) oacc[m][n] = (f32x4){0.f, 0.f, 0.f, 0.f};

    const int nt = qt * 2 + 2;   // KV tiles this block stages
    int cur = 0;

    // stage tile into buf: K rows (t-local, dh-contig) and Vt rows (dh, t-contig)
    auto stage = [&](int buf, int kv0) {
#pragma unroll
        for (int i = 0; i < 2; i++) {
            int slot = i * 256 + slot0;          // 0..511
            int row = slot >> 3, ch = slot & 7;
            int sc = ch ^ (row & 7);
            gload_lds16(&kp[(size_t)(kv0 + row) * DH_ + sc * 8], &sK[buf][(i * 256 + w * 64) * 8]);
            gload_lds16(&vp[(size_t)row * T_ + kv0 + sc * 8],    &sV[buf][(i * 256 + w * 64) * 8]);
        }
    };

    stage(0, 0);
    __syncthreads();   // tile 0 resident

    for (int t = 0; t < nt; ++t) {
        const int kv0 = t * 64;
        if (t + 1 < nt) stage(cur ^ 1, (t + 1) * 64);   // async prefetch
        if (kv0 <= qbase + 31) {
            // ---- QK^T ----
            f32x4 s[2][4];
#pragma unroll
            for (int sub = 0; sub < 4; sub++) {
                short8 bk0 = *swz_frag(sK[cur], sub * 16 + rsel, 0, g);
                short8 bk1 = *swz_frag(sK[cur], sub * 16 + rsel, 1, g);
#pragma unroll
                for (int m = 0; m < 2; m++) {
                    f32x4 t0 = (f32x4){0.f, 0.f, 0.f, 0.f};
                    t0 = __builtin_amdgcn_mfma_f32_16x16x32_bf16(aq[m][0], bk0, t0, 0, 0, 0);
                    t0 = __builtin_amdgcn_mfma_f32_16x16x32_bf16(aq[m][1], bk1, t0, 0, 0, 0);
                    s[m][sub] = t0;
                }
            }
            // ---- mask + online softmax (log2 domain) ----
#pragma unroll
            for (int m = 0; m < 2; m++) {
                float mx[4];
#pragma unroll
                for (int j = 0; j < 4; j++) {
                    int rg = qbase + m * 16 + rq + j;
#pragma unroll
                    for (int sub = 0; sub < 4; sub++) {
                        int cg = kv0 + sub * 16 + rsel;
                        if (cg > rg) s[m][sub][j] = -1e30f;
                    }
                    mx[j] = fmaxf(fmaxf(s[m][0][j], s[m][1][j]),
                                  fmaxf(s[m][2][j], s[m][3][j]));
                }
#pragma unroll
                for (int d = 1; d < 16; d <<= 1)
#pragma unroll
                    for (int j = 0; j < 4; j++) mx[j] = fmaxf(mx[j], __shfl_xor(mx[j], d));
#pragma unroll
                for (int j = 0; j < 4; j++) {
                    float mn = fmaxf(mr[m][j], mx[j]);
                    float al = exp2f(mr[m][j] - mn);   // exp2(-inf)=0 first tile
                    mr[m][j] = mn;
                    lr[m][j] *= al;
#pragma unroll
                    for (int n = 0; n < 4; n++) oacc[m][n][j] *= al;
#pragma unroll
                    for (int sub = 0; sub < 4; sub++) {
                        float p = exp2f(s[m][sub][j] - mn);
                        lr[m][j] += p;
                        pl[w][m * 16 + rq + j][sub * 16 + rsel] = f2bf(p);
                    }
                }
            }
            // ---- PV (P from per-wave LDS bounce; DS pipe is in-order) ----
#pragma unroll
            for (int ks = 0; ks < 2; ks++) {
                short8 ap[2];
#pragma unroll
                for (int m = 0; m < 2; m++) {
                    int row = m * 16 + rsel;
                    ap[m] = *reinterpret_cast<const short8*>(
                        reinterpret_cast<const char*>(&pl[w][0][0]) + row * 144 + ks * 64 + g * 16);
                }
#pragma unroll
                for (int n = 0; n < 4; n++) {
                    short8 bv = *swz_frag(sV[cur], n * 16 + rsel, ks, g);
#pragma unroll
                    for (int m = 0; m < 2; m++)
                        oacc[m][n] = __builtin_amdgcn_mfma_f32_16x16x32_bf16(ap[m], bv, oacc[m][n], 0, 0, 0);
                }
            }
        }
        __syncthreads();   // drains prefetch vmcnt + joins waves
        cur ^= 1;
    }

    // final row-sum reduce + output
#pragma unroll
    for (int m = 0; m < 2; m++)
#pragma unroll
        for (int d = 1; d < 16; d <<= 1)
#pragma unroll
            for (int j = 0; j < 4; j++) lr[m][j] += __shfl_xor(lr[m][j], d);

    const int bb = bh >> 4, h = bh & 15;
#pragma unroll
    for (int m = 0; m < 2; m++)
#pragma unroll
        for (int j = 0; j < 4; j++) {
            float inv = 1.0f / lr[m][j];
            int rg = qbase + m * 16 + rq + j;
#pragma unroll
            for (int n = 0; n < 4; n++)
                o[((size_t)(bb * T_ + rg)) * D_ + h * DH_ + n * 16 + rsel] =
                    f2bf(oacc[m][n][j] * inv);
        }
}

// ---------------------------------------------------------------------------
// Launch sequence
// ---------------------------------------------------------------------------
extern "C" void kernel_launch(void* const* d_in, const int* in_sizes, int n_in,
                              void* d_out, int out_size, void* d_ws, size_t ws_size,
                              hipStream_t stream)
{
    const float* x    = (const float*)d_in[0];
    const float* wq   = (const float*)d_in[1];
    const float* wk   = (const float*)d_in[2];
    const float* wv   = (const float*)d_in[3];
    const float* wo   = (const float*)d_in[4];
    const float* bo   = (const float*)d_in[5];
    const float* w1   = (const float*)d_in[6];
    const float* b1   = (const float*)d_in[7];
    const float* w2   = (const float*)d_in[8];
    const float* b2   = (const float*)d_in[9];
    const float* ln1s = (const float*)d_in[10];
    const float* ln1b = (const float*)d_in[11];
    const float* ln2s = (const float*)d_in[12];
    const float* ln2b = (const float*)d_in[13];
    float* out = (float*)d_out;

    char* ws = (char*)d_ws;
    unsigned short* wqkv_t = (unsigned short*)ws;                     // [3072][1024]
    unsigned short* wo_t   = wqkv_t + (size_t)3072 * 1024;            // [1024][1024]
    unsigned short* w1_t   = wo_t   + (size_t)1024 * 1024;            // [4096][1024]
    unsigned short* w2_t   = w1_t   + (size_t)4096 * 1024;            // [1024][4096]
    unsigned short* hbuf   = w2_t   + (size_t)1024 * 4096;            // [4096][1024]
    unsigned short* qb     = hbuf   + (size_t)4096 * 1024;            // (B,H,T,DH)
    unsigned short* kb     = qb     + (size_t)32 * 2048 * 64;
    unsigned short* vtb    = kb     + (size_t)32 * 2048 * 64;         // (B,H,DH,T)
    unsigned short* ao     = vtb    + (size_t)32 * 64 * 2048;         // (B,T,D)
    unsigned short* f1     = qb;    // reuse q|k|vt|ao span after attention+WO

    // weight converts (wq folded with 0.125 * log2(e) for exp2-domain softmax)
    cvt_t_kernel<<<dim3(16, 16), 256, 0, stream>>>(wq, wqkv_t,                   1024, 1024, 0.180336880111120425f);
    cvt_t_kernel<<<dim3(16, 16), 256, 0, stream>>>(wk, wqkv_t + 1024 * 1024,     1024, 1024, 1.f);
    cvt_t_kernel<<<dim3(16, 16), 256, 0, stream>>>(wv, wqkv_t + 2 * 1024 * 1024, 1024, 1024, 1.f);
    cvt_t_kernel<<<dim3(16, 16), 256, 0, stream>>>(wo, wo_t, 1024, 1024, 1.f);
    cvt_t_kernel<<<dim3(16, 64), 256, 0, stream>>>(w1, w1_t, 1024, 4096, 1.f);
    cvt_t_kernel<<<dim3(64, 16), 256, 0, stream>>>(w2, w2_t, 4096, 1024, 1.f);

    // attention sublayer
    ln_kernel<<<M_, 256, 0, stream>>>(x, ln1s, ln1b, hbuf);
    gemm_nt<EPI_QKV3, 1024, 3072><<<dim3(32, 24), 256, 0, stream>>>(
        hbuf, wqkv_t, qb, kb, vtb, nullptr, nullptr, nullptr);
    attn_kernel<<<dim3(16, 32), 256, 0, stream>>>(qb, kb, vtb, ao);
    gemm_nt<EPI_BIAS_RES, 1024, 1024><<<dim3(32, 8), 256, 0, stream>>>(
        ao, wo_t, nullptr, nullptr, nullptr, out, bo, x);   // out = x2

    // feed-forward sublayer
    ln_kernel<<<M_, 256, 0, stream>>>(out, ln2s, ln2b, hbuf);
    gemm_nt<EPI_BIAS_GELU, 1024, 4096><<<dim3(32, 32), 256, 0, stream>>>(
        hbuf, w1_t, f1, nullptr, nullptr, nullptr, b1, nullptr);
    gemm_nt<EPI_BIAS_RES, 4096, 1024><<<dim3(32, 8), 256, 0, stream>>>(
        f1, w2_t, nullptr, nullptr, nullptr, out, b2, out); // out = x2 + ff
}

// Round 3
// 314.268 us; speedup vs baseline: 1.5745x; 1.1431x over previous
//
#include <hip/hip_runtime.h>

// ---------------------------------------------------------------------------
// TransformerBlock (B=2, T=2048, D=1024, H=16, DH=64, DFF=4096) on gfx950.
// Round 3: causal load-balance remap, mask-split, defer-max (T13), trunc P,
// fast GELU. GEMM structure (m97: global_load_lds + XOR swizzle) unchanged.
// ---------------------------------------------------------------------------

#define B_   2
#define T_   2048
#define D_   1024
#define H_   16
#define DH_  64
#define DFF_ 4096
#define M_   4096   // B_*T_

typedef __attribute__((ext_vector_type(8))) short short8;   // 8 x bf16
typedef __attribute__((ext_vector_type(4))) float f32x4;    // MFMA accumulator

__device__ __forceinline__ unsigned short f2bf(float f) {
    union { float f; unsigned int u; } x; x.f = f;
    return (unsigned short)((x.u + 0x7FFFu + ((x.u >> 16) & 1u)) >> 16); // RNE
}
__device__ __forceinline__ unsigned short f2bf_trunc(float f) {
    union { float f; unsigned int u; } x; x.f = f;
    return (unsigned short)(x.u >> 16);   // truncation: 1 op; P is renormalized
}

__device__ __forceinline__ void gload_lds16(const unsigned short* g, unsigned short* l) {
    __builtin_amdgcn_global_load_lds(
        (const __attribute__((address_space(1))) void*)g,
        (__attribute__((address_space(3))) void*)l, 16, 0, 0);
}

// Swizzled fragment pointer into a [rows][64] bf16 tile (128 B rows).
// Storage swizzle: byte = row*128 + (chunk ^ (row&7))*16  (chunk = 16B unit).
__device__ __forceinline__ const short8* swz_frag(const unsigned short* base, int row, int ks, int g) {
    int byte = row * 128 + ((ks * 64 + g * 16) ^ ((row & 7) << 4));
    return reinterpret_cast<const short8*>(reinterpret_cast<const char*>(base) + byte);
}

// ---------------------------------------------------------------------------
// LayerNorm: fp32 row (D=1024) -> bf16 row.
// ---------------------------------------------------------------------------
__global__ __launch_bounds__(256) void ln_kernel(
    const float* __restrict__ in, const float* __restrict__ sc,
    const float* __restrict__ bi, unsigned short* __restrict__ out)
{
    __shared__ float ls[4], lq[4];
    const int row = blockIdx.x, t = threadIdx.x;
    const float* rp = in + (size_t)row * D_;
    float4 v = *reinterpret_cast<const float4*>(rp + t * 4);
    float s  = v.x + v.y + v.z + v.w;
    float sq = v.x * v.x + v.y * v.y + v.z * v.z + v.w * v.w;
#pragma unroll
    for (int d = 32; d > 0; d >>= 1) {
        s  += __shfl_down(s, d);
        sq += __shfl_down(sq, d);
    }
    if ((t & 63) == 0) { ls[t >> 6] = s; lq[t >> 6] = sq; }
    __syncthreads();
    s  = ls[0] + ls[1] + ls[2] + ls[3];
    sq = lq[0] + lq[1] + lq[2] + lq[3];
    float mean = s * (1.f / D_);
    float var  = fmaxf(sq * (1.f / D_) - mean * mean, 0.f);
    float inv  = 1.f / (sqrtf(var) + 1e-5f);
    float4 scv = *reinterpret_cast<const float4*>(sc + t * 4);
    float4 biv = *reinterpret_cast<const float4*>(bi + t * 4);
    ushort4 ov;
    ov.x = f2bf((v.x - mean) * inv * scv.x + biv.x);
    ov.y = f2bf((v.y - mean) * inv * scv.y + biv.y);
    ov.z = f2bf((v.z - mean) * inv * scv.z + biv.z);
    ov.w = f2bf((v.w - mean) * inv * scv.w + biv.w);
    *reinterpret_cast<ushort4*>(out + (size_t)row * D_ + t * 4) = ov;
}

// ---------------------------------------------------------------------------
// Convert fp32 [R][C] -> bf16 transposed [C][R], optional scale.
// ---------------------------------------------------------------------------
__global__ __launch_bounds__(256) void cvt_t_kernel(
    const float* __restrict__ in, unsigned short* __restrict__ out,
    int R, int C, float scale)
{
    __shared__ unsigned short lds[64][66];
    const int r0 = blockIdx.x * 64, c0 = blockIdx.y * 64;
#pragma unroll
    for (int i = 0; i < 16; i++) {
        int idx = threadIdx.x + i * 256;
        int r = idx >> 6, c = idx & 63;
        lds[r][c] = f2bf(in[(size_t)(r0 + r) * C + (c0 + c)] * scale);
    }
    __syncthreads();
#pragma unroll
    for (int i = 0; i < 16; i++) {
        int idx = threadIdx.x + i * 256;
        int r = idx >> 6, c = idx & 63;
        out[(size_t)(c0 + r) * R + (r0 + c)] = lds[c][r];
    }
}

// ---------------------------------------------------------------------------
// GEMM C[M,N] = A[M,K] * B^T[N,K]  (bf16 "NT"), 128x128 tile, BK=64, 4 waves.
// ---------------------------------------------------------------------------
enum { EPI_QKV3 = 0, EPI_BIAS_RES = 1, EPI_BIAS_GELU = 2 };

template <int EPI, int KDIM, int NDIM>
__global__ __launch_bounds__(256) void gemm_nt(
    const unsigned short* __restrict__ A,
    const unsigned short* __restrict__ Bt,
    unsigned short* __restrict__ out0,
    unsigned short* __restrict__ out1,
    unsigned short* __restrict__ out2,
    float* __restrict__ outF,
    const float* __restrict__ bias,
    const float* __restrict__ resid)
{
    __shared__ __align__(16) unsigned short sA[128 * 64];   // 16 KB, swizzled
    __shared__ __align__(16) unsigned short sB[128 * 64];
    const int tid = threadIdx.x, lane = tid & 63, w = tid >> 6;
    const int bm = blockIdx.x * 128, bn = blockIdx.y * 128;
    const int wm = (w >> 1) * 64, wn = (w & 1) * 64;
    const int rsel = lane & 15, g = lane >> 4;
    const int slot0 = w * 64 + lane;

    f32x4 acc[4][4];
#pragma unroll
    for (int m = 0; m < 4; m++)
#pragma unroll
        for (int n = 0; n < 4; n++) acc[m][n] = (f32x4){0.f, 0.f, 0.f, 0.f};

    for (int k0 = 0; k0 < KDIM; k0 += 64) {
        __syncthreads();
#pragma unroll
        for (int i = 0; i < 4; i++) {
            int slot = i * 256 + slot0;          // 0..1023
            int row = slot >> 3, ch = slot & 7;
            int sc = ch ^ (row & 7);             // inverse-swizzled source chunk
            gload_lds16(&A [(size_t)(bm + row) * KDIM + k0 + sc * 8], &sA[(i * 256 + w * 64) * 8]);
            gload_lds16(&Bt[(size_t)(bn + row) * KDIM + k0 + sc * 8], &sB[(i * 256 + w * 64) * 8]);
        }
        __syncthreads();
#pragma unroll
        for (int ks = 0; ks < 2; ks++) {
            short8 a[4], b[4];
#pragma unroll
            for (int m = 0; m < 4; m++) a[m] = *swz_frag(sA, wm + m * 16 + rsel, ks, g);
#pragma unroll
            for (int n = 0; n < 4; n++) b[n] = *swz_frag(sB, wn + n * 16 + rsel, ks, g);
#pragma unroll
            for (int m = 0; m < 4; m++)
#pragma unroll
                for (int n = 0; n < 4; n++)
                    acc[m][n] = __builtin_amdgcn_mfma_f32_16x16x32_bf16(a[m], b[n], acc[m][n], 0, 0, 0);
        }
    }

    const int rq = g * 4;
#pragma unroll
    for (int m = 0; m < 4; m++)
#pragma unroll
        for (int n = 0; n < 4; n++)
#pragma unroll
            for (int j = 0; j < 4; j++) {
                int rg = bm + wm + m * 16 + rq + j;   // global row (B*T)
                int cg = bn + wn + n * 16 + rsel;     // global col
                float v = acc[m][n][j];
                if constexpr (EPI == EPI_QKV3) {
                    int which = cg >> 10, col = cg & 1023;
                    int h = col >> 6, dh = col & 63;
                    int bb = rg >> 11, t = rg & 2047;
                    if (which == 0)
                        out0[(((size_t)(bb * H_ + h)) * T_ + t) * DH_ + dh] = f2bf(v);
                    else if (which == 1)
                        out1[(((size_t)(bb * H_ + h)) * T_ + t) * DH_ + dh] = f2bf(v);
                    else
                        out2[(((size_t)(bb * H_ + h)) * DH_ + dh) * T_ + t] = f2bf(v);
                } else if constexpr (EPI == EPI_BIAS_RES) {
                    v += bias[cg] + resid[(size_t)rg * NDIM + cg];
                    outF[(size_t)rg * NDIM + cg] = v;
                } else {
                    // fast GELU (tanh form via exp2): g = v - v/(1+e^{2u})
                    v += bias[cg];
                    float u = 0.7978845608028654f * (v + 0.044715f * v * v * v);
                    float e = exp2f(2.8853900817779268f * u);
                    v = v - v / (1.0f + e);
                    out0[(size_t)rg * NDIM + cg] = f2bf(v);
                }
            }
}

// ---------------------------------------------------------------------------
// Causal flash attention, bf16 MFMA, LDS-staged K/V (KVBLK=64, double buffer).
// Q pre-scaled by 0.125*log2(e); softmax in log2 domain (exp2).
// Block = 4 waves x 32 q-rows; grid flattened 512 with balance remap so each
// CU's two blocks pair qt with 15-qt (uniform per-CU work).
// ---------------------------------------------------------------------------
#define RESCALE_THR 8.0f

__global__ __launch_bounds__(256) void attn_kernel(
    const unsigned short* __restrict__ q,
    const unsigned short* __restrict__ k,
    const unsigned short* __restrict__ vt,
    unsigned short* __restrict__ o)
{
    __shared__ __align__(16) unsigned short sK[2][64 * 64];
    __shared__ __align__(16) unsigned short sV[2][64 * 64];
    __shared__ __align__(16) unsigned short pl[4][32][72];
    const int tid = threadIdx.x, lane = tid & 63, w = tid >> 6;

    // load-balance remap: CU gets qt and 15-qt pair
    const int bid  = blockIdx.x;           // 0..511
    const int half = bid >> 8, idx = bid & 255;
    const int qgrp = idx & 15;
    const int qt   = half ? (15 - qgrp) : qgrp;
    const int bh   = (idx >> 4) + half * 16;

    const int qbase = qt * 128 + w * 32;
    const unsigned short* qp = q  + (size_t)bh * T_ * DH_;
    const unsigned short* kp = k  + (size_t)bh * T_ * DH_;
    const unsigned short* vp = vt + (size_t)bh * DH_ * T_;
    const int rsel = lane & 15, g = lane >> 4, koff = g * 8, rq = g * 4;
    const int slot0 = w * 64 + lane;

    short8 aq[2][2];
#pragma unroll
    for (int m = 0; m < 2; m++)
#pragma unroll
        for (int ks = 0; ks < 2; ks++)
            aq[m][ks] = *reinterpret_cast<const short8*>(
                &qp[(size_t)(qbase + m * 16 + rsel) * DH_ + ks * 32 + koff]);

    float mr[2][4], lr[2][4];
    f32x4 oacc[2][4];
#pragma unroll
    for (int m = 0; m < 2; m++)
#pragma unroll
        for (int j = 0; j < 4; j++) { mr[m][j] = -INFINITY; lr[m][j] = 0.f; }
#pragma unroll
    for (int m = 0; m < 2; m++)
#pragma unroll
        for (int n = 0; n < 4; n++) oacc[m][n] = (f32x4){0.f, 0.f, 0.f, 0.f};

    const int nt = qt * 2 + 2;
    int cur = 0;

    auto stage = [&](int buf, int kv0) {
#pragma unroll
        for (int i = 0; i < 2; i++) {
            int slot = i * 256 + slot0;          // 0..511
            int row = slot >> 3, ch = slot & 7;
            int sc = ch ^ (row & 7);
            gload_lds16(&kp[(size_t)(kv0 + row) * DH_ + sc * 8], &sK[buf][(i * 256 + w * 64) * 8]);
            gload_lds16(&vp[(size_t)row * T_ + kv0 + sc * 8],    &sV[buf][(i * 256 + w * 64) * 8]);
        }
    };

    stage(0, 0);
    __syncthreads();

    for (int t = 0; t < nt; ++t) {
        const int kv0 = t * 64;
        if (t + 1 < nt) stage(cur ^ 1, (t + 1) * 64);
        if (kv0 <= qbase + 31) {
            // ---- QK^T ----
            f32x4 s[2][4];
#pragma unroll
            for (int sub = 0; sub < 4; sub++) {
                short8 bk0 = *swz_frag(sK[cur], sub * 16 + rsel, 0, g);
                short8 bk1 = *swz_frag(sK[cur], sub * 16 + rsel, 1, g);
#pragma unroll
                for (int m = 0; m < 2; m++) {
                    f32x4 t0 = (f32x4){0.f, 0.f, 0.f, 0.f};
                    t0 = __builtin_amdgcn_mfma_f32_16x16x32_bf16(aq[m][0], bk0, t0, 0, 0, 0);
                    t0 = __builtin_amdgcn_mfma_f32_16x16x32_bf16(aq[m][1], bk1, t0, 0, 0, 0);
                    s[m][sub] = t0;
                }
            }
            // ---- causal mask: only the diagonal-crossing tile needs it ----
            if (kv0 + 63 > qbase) {
#pragma unroll
                for (int m = 0; m < 2; m++)
#pragma unroll
                    for (int j = 0; j < 4; j++) {
                        int rg = qbase + m * 16 + rq + j;
#pragma unroll
                        for (int sub = 0; sub < 4; sub++) {
                            int cg = kv0 + sub * 16 + rsel;
                            if (cg > rg) s[m][sub][j] = -1e30f;
                        }
                    }
            }
            // ---- row max (within 16-lane col groups) ----
            float mx[2][4];
#pragma unroll
            for (int m = 0; m < 2; m++)
#pragma unroll
                for (int j = 0; j < 4; j++)
                    mx[m][j] = fmaxf(fmaxf(s[m][0][j], s[m][1][j]),
                                     fmaxf(s[m][2][j], s[m][3][j]));
#pragma unroll
            for (int d = 1; d < 16; d <<= 1)
#pragma unroll
                for (int m = 0; m < 2; m++)
#pragma unroll
                    for (int j = 0; j < 4; j++)
                        mx[m][j] = fmaxf(mx[m][j], __shfl_xor(mx[m][j], d));
            // ---- defer-max decision (wave-uniform after reduce) ----
            float growth = -INFINITY;
#pragma unroll
            for (int m = 0; m < 2; m++)
#pragma unroll
                for (int j = 0; j < 4; j++)
                    growth = fmaxf(growth, mx[m][j] - mr[m][j]);
            if (growth > RESCALE_THR) {   // includes first tile (mr = -inf)
#pragma unroll
                for (int m = 0; m < 2; m++)
#pragma unroll
                    for (int j = 0; j < 4; j++) {
                        float mn = fmaxf(mr[m][j], mx[m][j]);
                        float al = exp2f(mr[m][j] - mn);
                        mr[m][j] = mn;
                        lr[m][j] *= al;
#pragma unroll
                        for (int n = 0; n < 4; n++) oacc[m][n][j] *= al;
                    }
            }
            // ---- P = exp2(s - mr); bounded by 2^THR; truncating bf16 ----
#pragma unroll
            for (int m = 0; m < 2; m++)
#pragma unroll
                for (int j = 0; j < 4; j++) {
#pragma unroll
                    for (int sub = 0; sub < 4; sub++) {
                        float p = exp2f(s[m][sub][j] - mr[m][j]);
                        lr[m][j] += p;
                        pl[w][m * 16 + rq + j][sub * 16 + rsel] = f2bf_trunc(p);
                    }
                }
            // ---- PV ----
#pragma unroll
            for (int ks = 0; ks < 2; ks++) {
                short8 ap[2];
#pragma unroll
                for (int m = 0; m < 2; m++) {
                    int row = m * 16 + rsel;
                    ap[m] = *reinterpret_cast<const short8*>(
                        reinterpret_cast<const char*>(&pl[w][0][0]) + row * 144 + ks * 64 + g * 16);
                }
#pragma unroll
                for (int n = 0; n < 4; n++) {
                    short8 bv = *swz_frag(sV[cur], n * 16 + rsel, ks, g);
#pragma unroll
                    for (int m = 0; m < 2; m++)
                        oacc[m][n] = __builtin_amdgcn_mfma_f32_16x16x32_bf16(ap[m], bv, oacc[m][n], 0, 0, 0);
                }
            }
        }
        __syncthreads();
        cur ^= 1;
    }

#pragma unroll
    for (int m = 0; m < 2; m++)
#pragma unroll
        for (int d = 1; d < 16; d <<= 1)
#pragma unroll
            for (int j = 0; j < 4; j++) lr[m][j] += __shfl_xor(lr[m][j], d);

    const int bb = bh >> 4, h = bh & 15;
#pragma unroll
    for (int m = 0; m < 2; m++)
#pragma unroll
        for (int j = 0; j < 4; j++) {
            float inv = 1.0f / lr[m][j];
            int rg = qbase + m * 16 + rq + j;
#pragma unroll
            for (int n = 0; n < 4; n++)
                o[((size_t)(bb * T_ + rg)) * D_ + h * DH_ + n * 16 + rsel] =
                    f2bf(oacc[m][n][j] * inv);
        }
}

// ---------------------------------------------------------------------------
// Launch sequence
// ---------------------------------------------------------------------------
extern "C" void kernel_launch(void* const* d_in, const int* in_sizes, int n_in,
                              void* d_out, int out_size, void* d_ws, size_t ws_size,
                              hipStream_t stream)
{
    const float* x    = (const float*)d_in[0];
    const float* wq   = (const float*)d_in[1];
    const float* wk   = (const float*)d_in[2];
    const float* wv   = (const float*)d_in[3];
    const float* wo   = (const float*)d_in[4];
    const float* bo   = (const float*)d_in[5];
    const float* w1   = (const float*)d_in[6];
    const float* b1   = (const float*)d_in[7];
    const float* w2   = (const float*)d_in[8];
    const float* b2   = (const float*)d_in[9];
    const float* ln1s = (const float*)d_in[10];
    const float* ln1b = (const float*)d_in[11];
    const float* ln2s = (const float*)d_in[12];
    const float* ln2b = (const float*)d_in[13];
    float* out = (float*)d_out;

    char* ws = (char*)d_ws;
    unsigned short* wqkv_t = (unsigned short*)ws;                     // [3072][1024]
    unsigned short* wo_t   = wqkv_t + (size_t)3072 * 1024;            // [1024][1024]
    unsigned short* w1_t   = wo_t   + (size_t)1024 * 1024;            // [4096][1024]
    unsigned short* w2_t   = w1_t   + (size_t)4096 * 1024;            // [1024][4096]
    unsigned short* hbuf   = w2_t   + (size_t)1024 * 4096;            // [4096][1024]
    unsigned short* qb     = hbuf   + (size_t)4096 * 1024;            // (B,H,T,DH)
    unsigned short* kb     = qb     + (size_t)32 * 2048 * 64;
    unsigned short* vtb    = kb     + (size_t)32 * 2048 * 64;         // (B,H,DH,T)
    unsigned short* ao     = vtb    + (size_t)32 * 64 * 2048;         // (B,T,D)
    unsigned short* f1     = qb;    // reuse q|k|vt|ao span after attention+WO

    // weight converts (wq folded with 0.125 * log2(e) for exp2-domain softmax)
    cvt_t_kernel<<<dim3(16, 16), 256, 0, stream>>>(wq, wqkv_t,                   1024, 1024, 0.180336880111120425f);
    cvt_t_kernel<<<dim3(16, 16), 256, 0, stream>>>(wk, wqkv_t + 1024 * 1024,     1024, 1024, 1.f);
    cvt_t_kernel<<<dim3(16, 16), 256, 0, stream>>>(wv, wqkv_t + 2 * 1024 * 1024, 1024, 1024, 1.f);
    cvt_t_kernel<<<dim3(16, 16), 256, 0, stream>>>(wo, wo_t, 1024, 1024, 1.f);
    cvt_t_kernel<<<dim3(16, 64), 256, 0, stream>>>(w1, w1_t, 1024, 4096, 1.f);
    cvt_t_kernel<<<dim3(64, 16), 256, 0, stream>>>(w2, w2_t, 4096, 1024, 1.f);

    // attention sublayer
    ln_kernel<<<M_, 256, 0, stream>>>(x, ln1s, ln1b, hbuf);
    gemm_nt<EPI_QKV3, 1024, 3072><<<dim3(32, 24), 256, 0, stream>>>(
        hbuf, wqkv_t, qb, kb, vtb, nullptr, nullptr, nullptr);
    attn_kernel<<<512, 256, 0, stream>>>(qb, kb, vtb, ao);
    gemm_nt<EPI_BIAS_RES, 1024, 1024><<<dim3(32, 8), 256, 0, stream>>>(
        ao, wo_t, nullptr, nullptr, nullptr, out, bo, x);   // out = x2

    // feed-forward sublayer
    ln_kernel<<<M_, 256, 0, stream>>>(out, ln2s, ln2b, hbuf);
    gemm_nt<EPI_BIAS_GELU, 1024, 4096><<<dim3(32, 32), 256, 0, stream>>>(
        hbuf, w1_t, f1, nullptr, nullptr, nullptr, b1, nullptr);
    gemm_nt<EPI_BIAS_RES, 4096, 1024><<<dim3(32, 8), 256, 0, stream>>>(
        f1, w2_t, nullptr, nullptr, nullptr, out, b2, out); // out = x2 + ff
}

// Round 4
// 286.683 us; speedup vs baseline: 1.7260x; 1.0962x over previous
//
#include <hip/hip_runtime.h>

// ---------------------------------------------------------------------------
// TransformerBlock (B=2, T=2048, D=1024, H=16, DH=64, DFF=4096) on gfx950.
// Round 4: attn QBLK=64, 1024 balanced blocks, 40KB LDS -> 4 blocks/CU;
// swizzled P-bounce. GEMM: dbuf prefetch for the 1-block/CU dispatches
// (WO, FF2); QKV/FF1 keep 32KB + multi-block overlap.
// ---------------------------------------------------------------------------

#define B_   2
#define T_   2048
#define D_   1024
#define H_   16
#define DH_  64
#define DFF_ 4096
#define M_   4096   // B_*T_

typedef __attribute__((ext_vector_type(8))) short short8;   // 8 x bf16
typedef __attribute__((ext_vector_type(4))) float f32x4;    // MFMA accumulator

__device__ __forceinline__ unsigned short f2bf(float f) {
    union { float f; unsigned int u; } x; x.f = f;
    return (unsigned short)((x.u + 0x7FFFu + ((x.u >> 16) & 1u)) >> 16); // RNE
}
__device__ __forceinline__ unsigned short f2bf_trunc(float f) {
    union { float f; unsigned int u; } x; x.f = f;
    return (unsigned short)(x.u >> 16);   // P is renormalized; trunc is fine
}

__device__ __forceinline__ void gload_lds16(const unsigned short* g, unsigned short* l) {
    __builtin_amdgcn_global_load_lds(
        (const __attribute__((address_space(1))) void*)g,
        (__attribute__((address_space(3))) void*)l, 16, 0, 0);
}

// Swizzled fragment pointer into a [rows][64] bf16 tile (128 B rows).
// Storage swizzle: byte = row*128 + (chunk16 ^ (row&7))*16.
__device__ __forceinline__ const short8* swz_frag(const unsigned short* base, int row, int ks, int g) {
    int byte = row * 128 + ((ks * 64 + g * 16) ^ ((row & 7) << 4));
    return reinterpret_cast<const short8*>(reinterpret_cast<const char*>(base) + byte);
}

// ---------------------------------------------------------------------------
// LayerNorm: fp32 row (D=1024) -> bf16 row.
// ---------------------------------------------------------------------------
__global__ __launch_bounds__(256) void ln_kernel(
    const float* __restrict__ in, const float* __restrict__ sc,
    const float* __restrict__ bi, unsigned short* __restrict__ out)
{
    __shared__ float ls[4], lq[4];
    const int row = blockIdx.x, t = threadIdx.x;
    const float* rp = in + (size_t)row * D_;
    float4 v = *reinterpret_cast<const float4*>(rp + t * 4);
    float s  = v.x + v.y + v.z + v.w;
    float sq = v.x * v.x + v.y * v.y + v.z * v.z + v.w * v.w;
#pragma unroll
    for (int d = 32; d > 0; d >>= 1) {
        s  += __shfl_down(s, d);
        sq += __shfl_down(sq, d);
    }
    if ((t & 63) == 0) { ls[t >> 6] = s; lq[t >> 6] = sq; }
    __syncthreads();
    s  = ls[0] + ls[1] + ls[2] + ls[3];
    sq = lq[0] + lq[1] + lq[2] + lq[3];
    float mean = s * (1.f / D_);
    float var  = fmaxf(sq * (1.f / D_) - mean * mean, 0.f);
    float inv  = 1.f / (sqrtf(var) + 1e-5f);
    float4 scv = *reinterpret_cast<const float4*>(sc + t * 4);
    float4 biv = *reinterpret_cast<const float4*>(bi + t * 4);
    ushort4 ov;
    ov.x = f2bf((v.x - mean) * inv * scv.x + biv.x);
    ov.y = f2bf((v.y - mean) * inv * scv.y + biv.y);
    ov.z = f2bf((v.z - mean) * inv * scv.z + biv.z);
    ov.w = f2bf((v.w - mean) * inv * scv.w + biv.w);
    *reinterpret_cast<ushort4*>(out + (size_t)row * D_ + t * 4) = ov;
}

// ---------------------------------------------------------------------------
// Convert fp32 [R][C] -> bf16 transposed [C][R], optional scale.
// ---------------------------------------------------------------------------
__global__ __launch_bounds__(256) void cvt_t_kernel(
    const float* __restrict__ in, unsigned short* __restrict__ out,
    int R, int C, float scale)
{
    __shared__ unsigned short lds[64][66];
    const int r0 = blockIdx.x * 64, c0 = blockIdx.y * 64;
#pragma unroll
    for (int i = 0; i < 16; i++) {
        int idx = threadIdx.x + i * 256;
        int r = idx >> 6, c = idx & 63;
        lds[r][c] = f2bf(in[(size_t)(r0 + r) * C + (c0 + c)] * scale);
    }
    __syncthreads();
#pragma unroll
    for (int i = 0; i < 16; i++) {
        int idx = threadIdx.x + i * 256;
        int r = idx >> 6, c = idx & 63;
        out[(size_t)(c0 + r) * R + (r0 + c)] = lds[c][r];
    }
}

// ---------------------------------------------------------------------------
// GEMM C[M,N] = A[M,K] * B^T[N,K]  (bf16 "NT"), 128x128 tile, BK=64, 4 waves.
// DBUF=1: double-buffered LDS + async prefetch (for 1-block/CU dispatches).
// ---------------------------------------------------------------------------
enum { EPI_QKV3 = 0, EPI_BIAS_RES = 1, EPI_BIAS_GELU = 2 };

template <int EPI, int KDIM, int NDIM, int DBUF>
__global__ __launch_bounds__(256) void gemm_nt(
    const unsigned short* __restrict__ A,
    const unsigned short* __restrict__ Bt,
    unsigned short* __restrict__ out0,
    unsigned short* __restrict__ out1,
    unsigned short* __restrict__ out2,
    float* __restrict__ outF,
    const float* __restrict__ bias,
    const float* __restrict__ resid)
{
    __shared__ __align__(16) unsigned short sA[DBUF + 1][128 * 64];
    __shared__ __align__(16) unsigned short sB[DBUF + 1][128 * 64];
    const int tid = threadIdx.x, lane = tid & 63, w = tid >> 6;
    const int bm = blockIdx.x * 128, bn = blockIdx.y * 128;
    const int wm = (w >> 1) * 64, wn = (w & 1) * 64;
    const int rsel = lane & 15, g = lane >> 4;
    const int slot0 = w * 64 + lane;

    f32x4 acc[4][4];
#pragma unroll
    for (int m = 0; m < 4; m++)
#pragma unroll
        for (int n = 0; n < 4; n++) acc[m][n] = (f32x4){0.f, 0.f, 0.f, 0.f};

    auto stage = [&](int buf, int k0) {
#pragma unroll
        for (int i = 0; i < 4; i++) {
            int slot = i * 256 + slot0;          // 0..1023
            int row = slot >> 3, ch = slot & 7;
            int sc = ch ^ (row & 7);             // inverse-swizzled source chunk
            gload_lds16(&A [(size_t)(bm + row) * KDIM + k0 + sc * 8], &sA[buf][(i * 256 + w * 64) * 8]);
            gload_lds16(&Bt[(size_t)(bn + row) * KDIM + k0 + sc * 8], &sB[buf][(i * 256 + w * 64) * 8]);
        }
    };

    auto compute = [&](int buf) {
#pragma unroll
        for (int ks = 0; ks < 2; ks++) {
            short8 a[4], b[4];
#pragma unroll
            for (int m = 0; m < 4; m++) a[m] = *swz_frag(sA[buf], wm + m * 16 + rsel, ks, g);
#pragma unroll
            for (int n = 0; n < 4; n++) b[n] = *swz_frag(sB[buf], wn + n * 16 + rsel, ks, g);
#pragma unroll
            for (int m = 0; m < 4; m++)
#pragma unroll
                for (int n = 0; n < 4; n++)
                    acc[m][n] = __builtin_amdgcn_mfma_f32_16x16x32_bf16(a[m], b[n], acc[m][n], 0, 0, 0);
        }
    };

    if constexpr (DBUF) {
        constexpr int NK = KDIM / 64;
        int cur = 0;
        stage(0, 0);
        __syncthreads();   // drain -> tile 0 resident
        for (int kt = 0; kt < NK; ++kt) {
            if (kt + 1 < NK) stage(cur ^ 1, (kt + 1) * 64);   // prefetch (async)
            compute(cur);
            __syncthreads();  // drain (after compute: latency hidden) + join
            cur ^= 1;
        }
    } else {
        for (int k0 = 0; k0 < KDIM; k0 += 64) {
            __syncthreads();
            stage(0, k0);
            __syncthreads();
            compute(0);
        }
    }

    const int rq = g * 4;
#pragma unroll
    for (int m = 0; m < 4; m++)
#pragma unroll
        for (int n = 0; n < 4; n++)
#pragma unroll
            for (int j = 0; j < 4; j++) {
                int rg = bm + wm + m * 16 + rq + j;   // global row (B*T)
                int cg = bn + wn + n * 16 + rsel;     // global col
                float v = acc[m][n][j];
                if constexpr (EPI == EPI_QKV3) {
                    int which = cg >> 10, col = cg & 1023;
                    int h = col >> 6, dh = col & 63;
                    int bb = rg >> 11, t = rg & 2047;
                    if (which == 0)
                        out0[(((size_t)(bb * H_ + h)) * T_ + t) * DH_ + dh] = f2bf(v);
                    else if (which == 1)
                        out1[(((size_t)(bb * H_ + h)) * T_ + t) * DH_ + dh] = f2bf(v);
                    else
                        out2[(((size_t)(bb * H_ + h)) * DH_ + dh) * T_ + t] = f2bf(v);
                } else if constexpr (EPI == EPI_BIAS_RES) {
                    v += bias[cg] + resid[(size_t)rg * NDIM + cg];
                    outF[(size_t)rg * NDIM + cg] = v;
                } else {
                    // fast GELU (tanh form via exp2)
                    v += bias[cg];
                    float u = 0.7978845608028654f * (v + 0.044715f * v * v * v);
                    float e = exp2f(2.8853900817779268f * u);
                    v = v - v / (1.0f + e);
                    out0[(size_t)rg * NDIM + cg] = f2bf(v);
                }
            }
}

// ---------------------------------------------------------------------------
// Causal flash attention. QBLK=64 (4 waves x 16 q-rows), KVBLK=64 dbuf.
// Grid 1024 blocks, remapped so each CU's 4 resident blocks have qt set
// {s, 31-s, 8+s, 23-s} (uniform 66 tiles/CU, 4 overlapping chains/SIMD).
// LDS exactly 40KB -> 4 blocks/CU. P-bounce XOR-swizzled (conflict-free).
// ---------------------------------------------------------------------------
#define RESCALE_THR 8.0f

__global__ __launch_bounds__(256, 4) void attn_kernel(
    const unsigned short* __restrict__ q,
    const unsigned short* __restrict__ k,
    const unsigned short* __restrict__ vt,
    unsigned short* __restrict__ o)
{
    __shared__ __align__(16) unsigned short sK[2][64 * 64];   // 16 KB
    __shared__ __align__(16) unsigned short sV[2][64 * 64];   // 16 KB
    __shared__ __align__(16) unsigned short pl[4][1024];      //  8 KB (swizzled)
    const int tid = threadIdx.x, lane = tid & 63, w = tid >> 6;

    // balance remap
    const int u = blockIdx.x & 255, v = blockIdx.x >> 8;
    const int bh = u >> 3, strip = u & 7;
    const int qt = (v == 0) ? strip : (v == 1) ? 31 - strip
                 : (v == 2) ? 8 + strip : 23 - strip;

    const int qbase = qt * 64 + w * 16;
    const unsigned short* qp = q  + (size_t)bh * T_ * DH_;
    const unsigned short* kp = k  + (size_t)bh * T_ * DH_;
    const unsigned short* vp = vt + (size_t)bh * DH_ * T_;
    const int rsel = lane & 15, g = lane >> 4, koff = g * 8, rq = g * 4;
    const int slot0 = w * 64 + lane;

    short8 aq[2];
#pragma unroll
    for (int ks = 0; ks < 2; ks++)
        aq[ks] = *reinterpret_cast<const short8*>(
            &qp[(size_t)(qbase + rsel) * DH_ + ks * 32 + koff]);

    float mr[4], lr[4];
    f32x4 oacc[4];
#pragma unroll
    for (int j = 0; j < 4; j++) { mr[j] = -INFINITY; lr[j] = 0.f; }
#pragma unroll
    for (int n = 0; n < 4; n++) oacc[n] = (f32x4){0.f, 0.f, 0.f, 0.f};

    const int nt = qt + 1;
    int cur = 0;

    auto stage = [&](int buf, int kv0) {
#pragma unroll
        for (int i = 0; i < 2; i++) {
            int slot = i * 256 + slot0;          // 0..511
            int row = slot >> 3, ch = slot & 7;
            int sc = ch ^ (row & 7);
            gload_lds16(&kp[(size_t)(kv0 + row) * DH_ + sc * 8], &sK[buf][(i * 256 + w * 64) * 8]);
            gload_lds16(&vp[(size_t)row * T_ + kv0 + sc * 8],    &sV[buf][(i * 256 + w * 64) * 8]);
        }
    };

    stage(0, 0);
    __syncthreads();

    for (int t = 0; t < nt; ++t) {
        const int kv0 = t * 64;
        if (t + 1 < nt) stage(cur ^ 1, (t + 1) * 64);
        // ---- QK^T ----
        f32x4 s[4];
#pragma unroll
        for (int sub = 0; sub < 4; sub++) {
            short8 bk0 = *swz_frag(sK[cur], sub * 16 + rsel, 0, g);
            short8 bk1 = *swz_frag(sK[cur], sub * 16 + rsel, 1, g);
            f32x4 t0 = (f32x4){0.f, 0.f, 0.f, 0.f};
            t0 = __builtin_amdgcn_mfma_f32_16x16x32_bf16(aq[0], bk0, t0, 0, 0, 0);
            t0 = __builtin_amdgcn_mfma_f32_16x16x32_bf16(aq[1], bk1, t0, 0, 0, 0);
            s[sub] = t0;
        }
        // ---- causal mask: only the diagonal tile ----
        if (t == nt - 1) {
#pragma unroll
            for (int j = 0; j < 4; j++) {
                int rg = qbase + rq + j;
#pragma unroll
                for (int sub = 0; sub < 4; sub++) {
                    int cg = kv0 + sub * 16 + rsel;
                    if (cg > rg) s[sub][j] = -1e30f;
                }
            }
        }
        // ---- row max within 16-lane col groups ----
        float mx[4];
#pragma unroll
        for (int j = 0; j < 4; j++)
            mx[j] = fmaxf(fmaxf(s[0][j], s[1][j]), fmaxf(s[2][j], s[3][j]));
#pragma unroll
        for (int d = 1; d < 16; d <<= 1)
#pragma unroll
            for (int j = 0; j < 4; j++) mx[j] = fmaxf(mx[j], __shfl_xor(mx[j], d));
        // ---- defer-max ----
        float growth = -INFINITY;
#pragma unroll
        for (int j = 0; j < 4; j++) growth = fmaxf(growth, mx[j] - mr[j]);
        if (growth > RESCALE_THR) {
#pragma unroll
            for (int j = 0; j < 4; j++) {
                float mn = fmaxf(mr[j], mx[j]);
                float al = exp2f(mr[j] - mn);
                mr[j] = mn;
                lr[j] *= al;
#pragma unroll
                for (int n = 0; n < 4; n++) oacc[n][j] *= al;
            }
        }
        // ---- P = exp2(s - mr) -> swizzled LDS bounce ----
        unsigned short* plw = pl[w];
#pragma unroll
        for (int j = 0; j < 4; j++) {
            int row = rq + j;
            int rx = (row & 7) << 4;
#pragma unroll
            for (int sub = 0; sub < 4; sub++) {
                float p = exp2f(s[sub][j] - mr[j]);
                lr[j] += p;
                int byte = row * 128 + ((((sub * 16 + rsel) * 2)) ^ rx);
                plw[byte >> 1] = f2bf_trunc(p);
            }
        }
        // ---- PV ----
#pragma unroll
        for (int ks = 0; ks < 2; ks++) {
            int rbyte = rsel * 128 + ((ks * 64 + g * 16) ^ ((rsel & 7) << 4));
            short8 ap = *reinterpret_cast<const short8*>(
                reinterpret_cast<const char*>(plw) + rbyte);
#pragma unroll
            for (int n = 0; n < 4; n++) {
                short8 bv = *swz_frag(sV[cur], n * 16 + rsel, ks, g);
                oacc[n] = __builtin_amdgcn_mfma_f32_16x16x32_bf16(ap, bv, oacc[n], 0, 0, 0);
            }
        }
        __syncthreads();   // drain prefetch (hidden under compute) + join
        cur ^= 1;
    }

#pragma unroll
    for (int d = 1; d < 16; d <<= 1)
#pragma unroll
        for (int j = 0; j < 4; j++) lr[j] += __shfl_xor(lr[j], d);

    const int bb = bh >> 4, h = bh & 15;
#pragma unroll
    for (int j = 0; j < 4; j++) {
        float inv = 1.0f / lr[j];
        int rg = qbase + rq + j;
#pragma unroll
        for (int n = 0; n < 4; n++)
            o[((size_t)(bb * T_ + rg)) * D_ + h * DH_ + n * 16 + rsel] =
                f2bf(oacc[n][j] * inv);
    }
}

// ---------------------------------------------------------------------------
// Launch sequence
// ---------------------------------------------------------------------------
extern "C" void kernel_launch(void* const* d_in, const int* in_sizes, int n_in,
                              void* d_out, int out_size, void* d_ws, size_t ws_size,
                              hipStream_t stream)
{
    const float* x    = (const float*)d_in[0];
    const float* wq   = (const float*)d_in[1];
    const float* wk   = (const float*)d_in[2];
    const float* wv   = (const float*)d_in[3];
    const float* wo   = (const float*)d_in[4];
    const float* bo   = (const float*)d_in[5];
    const float* w1   = (const float*)d_in[6];
    const float* b1   = (const float*)d_in[7];
    const float* w2   = (const float*)d_in[8];
    const float* b2   = (const float*)d_in[9];
    const float* ln1s = (const float*)d_in[10];
    const float* ln1b = (const float*)d_in[11];
    const float* ln2s = (const float*)d_in[12];
    const float* ln2b = (const float*)d_in[13];
    float* out = (float*)d_out;

    char* ws = (char*)d_ws;
    unsigned short* wqkv_t = (unsigned short*)ws;                     // [3072][1024]
    unsigned short* wo_t   = wqkv_t + (size_t)3072 * 1024;            // [1024][1024]
    unsigned short* w1_t   = wo_t   + (size_t)1024 * 1024;            // [4096][1024]
    unsigned short* w2_t   = w1_t   + (size_t)4096 * 1024;            // [1024][4096]
    unsigned short* hbuf   = w2_t   + (size_t)1024 * 4096;            // [4096][1024]
    unsigned short* qb     = hbuf   + (size_t)4096 * 1024;            // (B,H,T,DH)
    unsigned short* kb     = qb     + (size_t)32 * 2048 * 64;
    unsigned short* vtb    = kb     + (size_t)32 * 2048 * 64;         // (B,H,DH,T)
    unsigned short* ao     = vtb    + (size_t)32 * 64 * 2048;         // (B,T,D)
    unsigned short* f1     = qb;    // reuse q|k|vt|ao span after attention+WO

    // weight converts (wq folded with 0.125 * log2(e) for exp2-domain softmax)
    cvt_t_kernel<<<dim3(16, 16), 256, 0, stream>>>(wq, wqkv_t,                   1024, 1024, 0.180336880111120425f);
    cvt_t_kernel<<<dim3(16, 16), 256, 0, stream>>>(wk, wqkv_t + 1024 * 1024,     1024, 1024, 1.f);
    cvt_t_kernel<<<dim3(16, 16), 256, 0, stream>>>(wv, wqkv_t + 2 * 1024 * 1024, 1024, 1024, 1.f);
    cvt_t_kernel<<<dim3(16, 16), 256, 0, stream>>>(wo, wo_t, 1024, 1024, 1.f);
    cvt_t_kernel<<<dim3(16, 64), 256, 0, stream>>>(w1, w1_t, 1024, 4096, 1.f);
    cvt_t_kernel<<<dim3(64, 16), 256, 0, stream>>>(w2, w2_t, 4096, 1024, 1.f);

    // attention sublayer
    ln_kernel<<<M_, 256, 0, stream>>>(x, ln1s, ln1b, hbuf);
    gemm_nt<EPI_QKV3, 1024, 3072, 0><<<dim3(32, 24), 256, 0, stream>>>(
        hbuf, wqkv_t, qb, kb, vtb, nullptr, nullptr, nullptr);
    attn_kernel<<<1024, 256, 0, stream>>>(qb, kb, vtb, ao);
    gemm_nt<EPI_BIAS_RES, 1024, 1024, 1><<<dim3(32, 8), 256, 0, stream>>>(
        ao, wo_t, nullptr, nullptr, nullptr, out, bo, x);   // out = x2
    // feed-forward sublayer
    ln_kernel<<<M_, 256, 0, stream>>>(out, ln2s, ln2b, hbuf);
    gemm_nt<EPI_BIAS_GELU, 1024, 4096, 0><<<dim3(32, 32), 256, 0, stream>>>(
        hbuf, w1_t, f1, nullptr, nullptr, nullptr, b1, nullptr);
    gemm_nt<EPI_BIAS_RES, 4096, 1024, 1><<<dim3(32, 8), 256, 0, stream>>>(
        f1, w2_t, nullptr, nullptr, nullptr, out, b2, out); // out = x2 + ff
}

// Round 7
// 263.306 us; speedup vs baseline: 1.8793x; 1.0888x over previous
//
#include <hip/hip_runtime.h>

// ---------------------------------------------------------------------------
// TransformerBlock (B=2, T=2048, D=1024, H=16, DH=64, DFF=4096) on gfx950.
// Round 5 (second retry; two consecutive container-infra failures, kernel
// never executed): templated GEMM tile (BM). WO/FF2 move to BM=64 tiles ->
// 512 blocks (2 blocks/CU, 2 waves/SIMD) + dbuf prefetch. QKV/FF1
// (3-4 blocks/CU) and attention unchanged.
// ---------------------------------------------------------------------------

#define B_   2
#define T_   2048
#define D_   1024
#define H_   16
#define DH_  64
#define DFF_ 4096
#define M_   4096   // B_*T_

typedef __attribute__((ext_vector_type(8))) short short8;   // 8 x bf16
typedef __attribute__((ext_vector_type(4))) float f32x4;    // MFMA accumulator

__device__ __forceinline__ unsigned short f2bf(float f) {
    union { float f; unsigned int u; } x; x.f = f;
    return (unsigned short)((x.u + 0x7FFFu + ((x.u >> 16) & 1u)) >> 16); // RNE
}
__device__ __forceinline__ unsigned short f2bf_trunc(float f) {
    union { float f; unsigned int u; } x; x.f = f;
    return (unsigned short)(x.u >> 16);   // P is renormalized; trunc is fine
}

__device__ __forceinline__ void gload_lds16(const unsigned short* g, unsigned short* l) {
    __builtin_amdgcn_global_load_lds(
        (const __attribute__((address_space(1))) void*)g,
        (__attribute__((address_space(3))) void*)l, 16, 0, 0);
}

// Swizzled fragment pointer into a [rows][64] bf16 tile (128 B rows).
// Storage swizzle: byte = row*128 + (chunk16 ^ (row&7))*16.
__device__ __forceinline__ const short8* swz_frag(const unsigned short* base, int row, int ks, int g) {
    int byte = row * 128 + ((ks * 64 + g * 16) ^ ((row & 7) << 4));
    return reinterpret_cast<const short8*>(reinterpret_cast<const char*>(base) + byte);
}

// ---------------------------------------------------------------------------
// LayerNorm: fp32 row (D=1024) -> bf16 row.
// ---------------------------------------------------------------------------
__global__ __launch_bounds__(256) void ln_kernel(
    const float* __restrict__ in, const float* __restrict__ sc,
    const float* __restrict__ bi, unsigned short* __restrict__ out)
{
    __shared__ float ls[4], lq[4];
    const int row = blockIdx.x, t = threadIdx.x;
    const float* rp = in + (size_t)row * D_;
    float4 v = *reinterpret_cast<const float4*>(rp + t * 4);
    float s  = v.x + v.y + v.z + v.w;
    float sq = v.x * v.x + v.y * v.y + v.z * v.z + v.w * v.w;
#pragma unroll
    for (int d = 32; d > 0; d >>= 1) {
        s  += __shfl_down(s, d);
        sq += __shfl_down(sq, d);
    }
    if ((t & 63) == 0) { ls[t >> 6] = s; lq[t >> 6] = sq; }
    __syncthreads();
    s  = ls[0] + ls[1] + ls[2] + ls[3];
    sq = lq[0] + lq[1] + lq[2] + lq[3];
    float mean = s * (1.f / D_);
    float var  = fmaxf(sq * (1.f / D_) - mean * mean, 0.f);
    float inv  = 1.f / (sqrtf(var) + 1e-5f);
    float4 scv = *reinterpret_cast<const float4*>(sc + t * 4);
    float4 biv = *reinterpret_cast<const float4*>(bi + t * 4);
    ushort4 ov;
    ov.x = f2bf((v.x - mean) * inv * scv.x + biv.x);
    ov.y = f2bf((v.y - mean) * inv * scv.y + biv.y);
    ov.z = f2bf((v.z - mean) * inv * scv.z + biv.z);
    ov.w = f2bf((v.w - mean) * inv * scv.w + biv.w);
    *reinterpret_cast<ushort4*>(out + (size_t)row * D_ + t * 4) = ov;
}

// ---------------------------------------------------------------------------
// Convert fp32 [R][C] -> bf16 transposed [C][R], optional scale.
// ---------------------------------------------------------------------------
__global__ __launch_bounds__(256) void cvt_t_kernel(
    const float* __restrict__ in, unsigned short* __restrict__ out,
    int R, int C, float scale)
{
    __shared__ unsigned short lds[64][66];
    const int r0 = blockIdx.x * 64, c0 = blockIdx.y * 64;
#pragma unroll
    for (int i = 0; i < 16; i++) {
        int idx = threadIdx.x + i * 256;
        int r = idx >> 6, c = idx & 63;
        lds[r][c] = f2bf(in[(size_t)(r0 + r) * C + (c0 + c)] * scale);
    }
    __syncthreads();
#pragma unroll
    for (int i = 0; i < 16; i++) {
        int idx = threadIdx.x + i * 256;
        int r = idx >> 6, c = idx & 63;
        out[(size_t)(c0 + r) * R + (r0 + c)] = lds[c][r];
    }
}

// ---------------------------------------------------------------------------
// GEMM C[M,N] = A[M,K] * B^T[N,K]  (bf16 "NT"), BMx128 tile, BK=64, 4 waves.
// BM=128: wave tile 64x64 (acc 4x4). BM=64: wave tile 32x64 (acc 2x4),
// grid doubles in M -> 2+ blocks/CU for the N=1024 GEMMs.
// DBUF=1: double-buffered LDS + async prefetch.
// ---------------------------------------------------------------------------
enum { EPI_QKV3 = 0, EPI_BIAS_RES = 1, EPI_BIAS_GELU = 2 };

template <int EPI, int KDIM, int NDIM, int DBUF, int BM>
__global__ __launch_bounds__(256) void gemm_nt(
    const unsigned short* __restrict__ A,
    const unsigned short* __restrict__ Bt,
    unsigned short* __restrict__ out0,
    unsigned short* __restrict__ out1,
    unsigned short* __restrict__ out2,
    float* __restrict__ outF,
    const float* __restrict__ bias,
    const float* __restrict__ resid)
{
    constexpr int MF = BM / 32;        // m-fragments per wave
    constexpr int IA = BM / 32;        // A staging rounds (BM*8 chunks / 256)
    __shared__ __align__(16) unsigned short sA[DBUF + 1][BM * 64];
    __shared__ __align__(16) unsigned short sB[DBUF + 1][128 * 64];
    const int tid = threadIdx.x, lane = tid & 63, w = tid >> 6;
    const int bm = blockIdx.x * BM, bn = blockIdx.y * 128;
    const int wm = (w >> 1) * (BM / 2), wn = (w & 1) * 64;
    const int rsel = lane & 15, g = lane >> 4;
    const int slot0 = w * 64 + lane;

    f32x4 acc[MF][4];
#pragma unroll
    for (int m = 0; m < MF; m++)
#pragma unroll
        for (int n = 0; n < 4; n++) acc[m][n] = (f32x4){0.f, 0.f, 0.f, 0.f};

    auto stage = [&](int buf, int k0) {
#pragma unroll
        for (int i = 0; i < IA; i++) {
            int slot = i * 256 + slot0;          // 0..BM*8-1
            int row = slot >> 3, ch = slot & 7;
            int sc = ch ^ (row & 7);             // inverse-swizzled source chunk
            gload_lds16(&A[(size_t)(bm + row) * KDIM + k0 + sc * 8], &sA[buf][(i * 256 + w * 64) * 8]);
        }
#pragma unroll
        for (int i = 0; i < 4; i++) {
            int slot = i * 256 + slot0;          // 0..1023
            int row = slot >> 3, ch = slot & 7;
            int sc = ch ^ (row & 7);
            gload_lds16(&Bt[(size_t)(bn + row) * KDIM + k0 + sc * 8], &sB[buf][(i * 256 + w * 64) * 8]);
        }
    };

    auto compute = [&](int buf) {
#pragma unroll
        for (int ks = 0; ks < 2; ks++) {
            short8 a[MF], b[4];
#pragma unroll
            for (int m = 0; m < MF; m++) a[m] = *swz_frag(sA[buf], wm + m * 16 + rsel, ks, g);
#pragma unroll
            for (int n = 0; n < 4; n++) b[n] = *swz_frag(sB[buf], wn + n * 16 + rsel, ks, g);
#pragma unroll
            for (int m = 0; m < MF; m++)
#pragma unroll
                for (int n = 0; n < 4; n++)
                    acc[m][n] = __builtin_amdgcn_mfma_f32_16x16x32_bf16(a[m], b[n], acc[m][n], 0, 0, 0);
        }
    };

    if constexpr (DBUF) {
        constexpr int NK = KDIM / 64;
        int cur = 0;
        stage(0, 0);
        __syncthreads();   // drain -> tile 0 resident
        for (int kt = 0; kt < NK; ++kt) {
            if (kt + 1 < NK) stage(cur ^ 1, (kt + 1) * 64);   // prefetch (async)
            compute(cur);
            __syncthreads();  // drain lands after compute: latency hidden
            cur ^= 1;
        }
    } else {
        for (int k0 = 0; k0 < KDIM; k0 += 64) {
            __syncthreads();
            stage(0, k0);
            __syncthreads();
            compute(0);
        }
    }

    const int rq = g * 4;
#pragma unroll
    for (int m = 0; m < MF; m++)
#pragma unroll
        for (int n = 0; n < 4; n++)
#pragma unroll
            for (int j = 0; j < 4; j++) {
                int rg = bm + wm + m * 16 + rq + j;   // global row (B*T)
                int cg = bn + wn + n * 16 + rsel;     // global col
                float v = acc[m][n][j];
                if constexpr (EPI == EPI_QKV3) {
                    int which = cg >> 10, col = cg & 1023;
                    int h = col >> 6, dh = col & 63;
                    int bb = rg >> 11, t = rg & 2047;
                    if (which == 0)
                        out0[(((size_t)(bb * H_ + h)) * T_ + t) * DH_ + dh] = f2bf(v);
                    else if (which == 1)
                        out1[(((size_t)(bb * H_ + h)) * T_ + t) * DH_ + dh] = f2bf(v);
                    else
                        out2[(((size_t)(bb * H_ + h)) * DH_ + dh) * T_ + t] = f2bf(v);
                } else if constexpr (EPI == EPI_BIAS_RES) {
                    v += bias[cg] + resid[(size_t)rg * NDIM + cg];
                    outF[(size_t)rg * NDIM + cg] = v;
                } else {
                    // fast GELU (tanh form via exp2)
                    v += bias[cg];
                    float u = 0.7978845608028654f * (v + 0.044715f * v * v * v);
                    float e = exp2f(2.8853900817779268f * u);
                    v = v - v / (1.0f + e);
                    out0[(size_t)rg * NDIM + cg] = f2bf(v);
                }
            }
}

// ---------------------------------------------------------------------------
// Causal flash attention. QBLK=64 (4 waves x 16 q-rows), KVBLK=64 dbuf.
// Grid 1024 blocks, remapped so each CU's 4 resident blocks have qt set
// {s, 31-s, 8+s, 23-s}. LDS 40KB -> 4 blocks/CU. Swizzled P-bounce.
// ---------------------------------------------------------------------------
#define RESCALE_THR 8.0f

__global__ __launch_bounds__(256, 4) void attn_kernel(
    const unsigned short* __restrict__ q,
    const unsigned short* __restrict__ k,
    const unsigned short* __restrict__ vt,
    unsigned short* __restrict__ o)
{
    __shared__ __align__(16) unsigned short sK[2][64 * 64];   // 16 KB
    __shared__ __align__(16) unsigned short sV[2][64 * 64];   // 16 KB
    __shared__ __align__(16) unsigned short pl[4][1024];      //  8 KB (swizzled)
    const int tid = threadIdx.x, lane = tid & 63, w = tid >> 6;

    // balance remap
    const int u = blockIdx.x & 255, v = blockIdx.x >> 8;
    const int bh = u >> 3, strip = u & 7;
    const int qt = (v == 0) ? strip : (v == 1) ? 31 - strip
                 : (v == 2) ? 8 + strip : 23 - strip;

    const int qbase = qt * 64 + w * 16;
    const unsigned short* qp = q  + (size_t)bh * T_ * DH_;
    const unsigned short* kp = k  + (size_t)bh * T_ * DH_;
    const unsigned short* vp = vt + (size_t)bh * DH_ * T_;
    const int rsel = lane & 15, g = lane >> 4, koff = g * 8, rq = g * 4;
    const int slot0 = w * 64 + lane;

    short8 aq[2];
#pragma unroll
    for (int ks = 0; ks < 2; ks++)
        aq[ks] = *reinterpret_cast<const short8*>(
            &qp[(size_t)(qbase + rsel) * DH_ + ks * 32 + koff]);

    float mr[4], lr[4];
    f32x4 oacc[4];
#pragma unroll
    for (int j = 0; j < 4; j++) { mr[j] = -INFINITY; lr[j] = 0.f; }
#pragma unroll
    for (int n = 0; n < 4; n++) oacc[n] = (f32x4){0.f, 0.f, 0.f, 0.f};

    const int nt = qt + 1;
    int cur = 0;

    auto stage = [&](int buf, int kv0) {
#pragma unroll
        for (int i = 0; i < 2; i++) {
            int slot = i * 256 + slot0;          // 0..511
            int row = slot >> 3, ch = slot & 7;
            int sc = ch ^ (row & 7);
            gload_lds16(&kp[(size_t)(kv0 + row) * DH_ + sc * 8], &sK[buf][(i * 256 + w * 64) * 8]);
            gload_lds16(&vp[(size_t)row * T_ + kv0 + sc * 8],    &sV[buf][(i * 256 + w * 64) * 8]);
        }
    };

    stage(0, 0);
    __syncthreads();

    for (int t = 0; t < nt; ++t) {
        const int kv0 = t * 64;
        if (t + 1 < nt) stage(cur ^ 1, (t + 1) * 64);
        // ---- QK^T ----
        f32x4 s[4];
#pragma unroll
        for (int sub = 0; sub < 4; sub++) {
            short8 bk0 = *swz_frag(sK[cur], sub * 16 + rsel, 0, g);
            short8 bk1 = *swz_frag(sK[cur], sub * 16 + rsel, 1, g);
            f32x4 t0 = (f32x4){0.f, 0.f, 0.f, 0.f};
            t0 = __builtin_amdgcn_mfma_f32_16x16x32_bf16(aq[0], bk0, t0, 0, 0, 0);
            t0 = __builtin_amdgcn_mfma_f32_16x16x32_bf16(aq[1], bk1, t0, 0, 0, 0);
            s[sub] = t0;
        }
        // ---- causal mask: only the diagonal tile ----
        if (t == nt - 1) {
#pragma unroll
            for (int j = 0; j < 4; j++) {
                int rg = qbase + rq + j;
#pragma unroll
                for (int sub = 0; sub < 4; sub++) {
                    int cg = kv0 + sub * 16 + rsel;
                    if (cg > rg) s[sub][j] = -1e30f;
                }
            }
        }
        // ---- row max within 16-lane col groups ----
        float mx[4];
#pragma unroll
        for (int j = 0; j < 4; j++)
            mx[j] = fmaxf(fmaxf(s[0][j], s[1][j]), fmaxf(s[2][j], s[3][j]));
#pragma unroll
        for (int d = 1; d < 16; d <<= 1)
#pragma unroll
            for (int j = 0; j < 4; j++) mx[j] = fmaxf(mx[j], __shfl_xor(mx[j], d));
        // ---- defer-max ----
        float growth = -INFINITY;
#pragma unroll
        for (int j = 0; j < 4; j++) growth = fmaxf(growth, mx[j] - mr[j]);
        if (growth > RESCALE_THR) {
#pragma unroll
            for (int j = 0; j < 4; j++) {
                float mn = fmaxf(mr[j], mx[j]);
                float al = exp2f(mr[j] - mn);
                mr[j] = mn;
                lr[j] *= al;
#pragma unroll
                for (int n = 0; n < 4; n++) oacc[n][j] *= al;
            }
        }
        // ---- P = exp2(s - mr) -> swizzled LDS bounce ----
        unsigned short* plw = pl[w];
#pragma unroll
        for (int j = 0; j < 4; j++) {
            int row = rq + j;
            int rx = (row & 7) << 4;
#pragma unroll
            for (int sub = 0; sub < 4; sub++) {
                float p = exp2f(s[sub][j] - mr[j]);
                lr[j] += p;
                int byte = row * 128 + ((((sub * 16 + rsel) * 2)) ^ rx);
                plw[byte >> 1] = f2bf_trunc(p);
            }
        }
        // ---- PV ----
#pragma unroll
        for (int ks = 0; ks < 2; ks++) {
            int rbyte = rsel * 128 + ((ks * 64 + g * 16) ^ ((rsel & 7) << 4));
            short8 ap = *reinterpret_cast<const short8*>(
                reinterpret_cast<const char*>(plw) + rbyte);
#pragma unroll
            for (int n = 0; n < 4; n++) {
                short8 bv = *swz_frag(sV[cur], n * 16 + rsel, ks, g);
                oacc[n] = __builtin_amdgcn_mfma_f32_16x16x32_bf16(ap, bv, oacc[n], 0, 0, 0);
            }
        }
        __syncthreads();   // drain prefetch (hidden under compute) + join
        cur ^= 1;
    }

#pragma unroll
    for (int d = 1; d < 16; d <<= 1)
#pragma unroll
        for (int j = 0; j < 4; j++) lr[j] += __shfl_xor(lr[j], d);

    const int bb = bh >> 4, h = bh & 15;
#pragma unroll
    for (int j = 0; j < 4; j++) {
        float inv = 1.0f / lr[j];
        int rg = qbase + rq + j;
#pragma unroll
        for (int n = 0; n < 4; n++)
            o[((size_t)(bb * T_ + rg)) * D_ + h * DH_ + n * 16 + rsel] =
                f2bf(oacc[n][j] * inv);
    }
}

// ---------------------------------------------------------------------------
// Launch sequence
// ---------------------------------------------------------------------------
extern "C" void kernel_launch(void* const* d_in, const int* in_sizes, int n_in,
                              void* d_out, int out_size, void* d_ws, size_t ws_size,
                              hipStream_t stream)
{
    const float* x    = (const float*)d_in[0];
    const float* wq   = (const float*)d_in[1];
    const float* wk   = (const float*)d_in[2];
    const float* wv   = (const float*)d_in[3];
    const float* wo   = (const float*)d_in[4];
    const float* bo   = (const float*)d_in[5];
    const float* w1   = (const float*)d_in[6];
    const float* b1   = (const float*)d_in[7];
    const float* w2   = (const float*)d_in[8];
    const float* b2   = (const float*)d_in[9];
    const float* ln1s = (const float*)d_in[10];
    const float* ln1b = (const float*)d_in[11];
    const float* ln2s = (const float*)d_in[12];
    const float* ln2b = (const float*)d_in[13];
    float* out = (float*)d_out;

    char* ws = (char*)d_ws;
    unsigned short* wqkv_t = (unsigned short*)ws;                     // [3072][1024]
    unsigned short* wo_t   = wqkv_t + (size_t)3072 * 1024;            // [1024][1024]
    unsigned short* w1_t   = wo_t   + (size_t)1024 * 1024;            // [4096][1024]
    unsigned short* w2_t   = w1_t   + (size_t)4096 * 1024;            // [1024][4096]
    unsigned short* hbuf   = w2_t   + (size_t)1024 * 4096;            // [4096][1024]
    unsigned short* qb     = hbuf   + (size_t)4096 * 1024;            // (B,H,T,DH)
    unsigned short* kb     = qb     + (size_t)32 * 2048 * 64;
    unsigned short* vtb    = kb     + (size_t)32 * 2048 * 64;         // (B,H,DH,T)
    unsigned short* ao     = vtb    + (size_t)32 * 64 * 2048;         // (B,T,D)
    unsigned short* f1     = qb;    // reuse q|k|vt|ao span after attention+WO

    // weight converts (wq folded with 0.125 * log2(e) for exp2-domain softmax)
    cvt_t_kernel<<<dim3(16, 16), 256, 0, stream>>>(wq, wqkv_t,                   1024, 1024, 0.180336880111120425f);
    cvt_t_kernel<<<dim3(16, 16), 256, 0, stream>>>(wk, wqkv_t + 1024 * 1024,     1024, 1024, 1.f);
    cvt_t_kernel<<<dim3(16, 16), 256, 0, stream>>>(wv, wqkv_t + 2 * 1024 * 1024, 1024, 1024, 1.f);
    cvt_t_kernel<<<dim3(16, 16), 256, 0, stream>>>(wo, wo_t, 1024, 1024, 1.f);
    cvt_t_kernel<<<dim3(16, 64), 256, 0, stream>>>(w1, w1_t, 1024, 4096, 1.f);
    cvt_t_kernel<<<dim3(64, 16), 256, 0, stream>>>(w2, w2_t, 4096, 1024, 1.f);

    // attention sublayer
    ln_kernel<<<M_, 256, 0, stream>>>(x, ln1s, ln1b, hbuf);
    gemm_nt<EPI_QKV3, 1024, 3072, 0, 128><<<dim3(32, 24), 256, 0, stream>>>(
        hbuf, wqkv_t, qb, kb, vtb, nullptr, nullptr, nullptr);
    attn_kernel<<<1024, 256, 0, stream>>>(qb, kb, vtb, ao);
    gemm_nt<EPI_BIAS_RES, 1024, 1024, 1, 64><<<dim3(64, 8), 256, 0, stream>>>(
        ao, wo_t, nullptr, nullptr, nullptr, out, bo, x);   // out = x2
    // feed-forward sublayer
    ln_kernel<<<M_, 256, 0, stream>>>(out, ln2s, ln2b, hbuf);
    gemm_nt<EPI_BIAS_GELU, 1024, 4096, 0, 128><<<dim3(32, 32), 256, 0, stream>>>(
        hbuf, w1_t, f1, nullptr, nullptr, nullptr, b1, nullptr);
    gemm_nt<EPI_BIAS_RES, 4096, 1024, 1, 64><<<dim3(64, 8), 256, 0, stream>>>(
        f1, w2_t, nullptr, nullptr, nullptr, out, b2, out); // out = x2 + ff
}

// Round 8
// 248.889 us; speedup vs baseline: 1.9881x; 1.0579x over previous
//
#include <hip/hip_runtime.h>

// ---------------------------------------------------------------------------
// TransformerBlock (B=2, T=2048, D=1024, H=16, DH=64, DFF=4096) on gfx950.
// Round 8: attn swapped-QK^T (kv lane-local softmax, O^T PV, packed P bounce)
// + XCD-aware head-colocated remap; FF2 split-K=2 (4 blocks/CU) + addp reduce.
// ---------------------------------------------------------------------------

#define B_   2
#define T_   2048
#define D_   1024
#define H_   16
#define DH_  64
#define DFF_ 4096
#define M_   4096   // B_*T_

typedef __attribute__((ext_vector_type(8))) short short8;   // 8 x bf16
typedef __attribute__((ext_vector_type(4))) float f32x4;    // MFMA accumulator

__device__ __forceinline__ unsigned short f2bf(float f) {
    union { float f; unsigned int u; } x; x.f = f;
    return (unsigned short)((x.u + 0x7FFFu + ((x.u >> 16) & 1u)) >> 16); // RNE
}
__device__ __forceinline__ unsigned int f2bf_trunc(float f) {
    union { float f; unsigned int u; } x; x.f = f;
    return x.u >> 16;   // P is renormalized; trunc is fine
}

__device__ __forceinline__ void gload_lds16(const unsigned short* g, unsigned short* l) {
    __builtin_amdgcn_global_load_lds(
        (const __attribute__((address_space(1))) void*)g,
        (__attribute__((address_space(3))) void*)l, 16, 0, 0);
}

// Swizzled fragment pointer into a [rows][64] bf16 tile (128 B rows).
// Storage swizzle: byte = row*128 + (chunk16 ^ (row&7))*16.
__device__ __forceinline__ const short8* swz_frag(const unsigned short* base, int row, int ks, int g) {
    int byte = row * 128 + ((ks * 64 + g * 16) ^ ((row & 7) << 4));
    return reinterpret_cast<const short8*>(reinterpret_cast<const char*>(base) + byte);
}

// ---------------------------------------------------------------------------
// LayerNorm: fp32 row (D=1024) -> bf16 row.
// ---------------------------------------------------------------------------
__global__ __launch_bounds__(256) void ln_kernel(
    const float* __restrict__ in, const float* __restrict__ sc,
    const float* __restrict__ bi, unsigned short* __restrict__ out)
{
    __shared__ float ls[4], lq[4];
    const int row = blockIdx.x, t = threadIdx.x;
    const float* rp = in + (size_t)row * D_;
    float4 v = *reinterpret_cast<const float4*>(rp + t * 4);
    float s  = v.x + v.y + v.z + v.w;
    float sq = v.x * v.x + v.y * v.y + v.z * v.z + v.w * v.w;
#pragma unroll
    for (int d = 32; d > 0; d >>= 1) {
        s  += __shfl_down(s, d);
        sq += __shfl_down(sq, d);
    }
    if ((t & 63) == 0) { ls[t >> 6] = s; lq[t >> 6] = sq; }
    __syncthreads();
    s  = ls[0] + ls[1] + ls[2] + ls[3];
    sq = lq[0] + lq[1] + lq[2] + lq[3];
    float mean = s * (1.f / D_);
    float var  = fmaxf(sq * (1.f / D_) - mean * mean, 0.f);
    float inv  = 1.f / (sqrtf(var) + 1e-5f);
    float4 scv = *reinterpret_cast<const float4*>(sc + t * 4);
    float4 biv = *reinterpret_cast<const float4*>(bi + t * 4);
    ushort4 ov;
    ov.x = f2bf((v.x - mean) * inv * scv.x + biv.x);
    ov.y = f2bf((v.y - mean) * inv * scv.y + biv.y);
    ov.z = f2bf((v.z - mean) * inv * scv.z + biv.z);
    ov.w = f2bf((v.w - mean) * inv * scv.w + biv.w);
    *reinterpret_cast<ushort4*>(out + (size_t)row * D_ + t * 4) = ov;
}

// ---------------------------------------------------------------------------
// Convert fp32 [R][C] -> bf16 transposed [C][R], optional scale.
// ---------------------------------------------------------------------------
__global__ __launch_bounds__(256) void cvt_t_kernel(
    const float* __restrict__ in, unsigned short* __restrict__ out,
    int R, int C, float scale)
{
    __shared__ unsigned short lds[64][66];
    const int r0 = blockIdx.x * 64, c0 = blockIdx.y * 64;
#pragma unroll
    for (int i = 0; i < 16; i++) {
        int idx = threadIdx.x + i * 256;
        int r = idx >> 6, c = idx & 63;
        lds[r][c] = f2bf(in[(size_t)(r0 + r) * C + (c0 + c)] * scale);
    }
    __syncthreads();
#pragma unroll
    for (int i = 0; i < 16; i++) {
        int idx = threadIdx.x + i * 256;
        int r = idx >> 6, c = idx & 63;
        out[(size_t)(c0 + r) * R + (r0 + c)] = lds[c][r];
    }
}

// ---------------------------------------------------------------------------
// fp32 out[i] += partial[i]  (split-K reduce), float4 grid-stride.
// ---------------------------------------------------------------------------
__global__ __launch_bounds__(256) void addp_kernel(
    float* __restrict__ out, const float* __restrict__ p)
{
    const int n4 = (M_ * D_) / 4;
    int i = blockIdx.x * 256 + threadIdx.x;
    const int stride = gridDim.x * 256;
    for (; i < n4; i += stride) {
        float4 a = reinterpret_cast<float4*>(out)[i];
        float4 b = reinterpret_cast<const float4*>(p)[i];
        a.x += b.x; a.y += b.y; a.z += b.z; a.w += b.w;
        reinterpret_cast<float4*>(out)[i] = a;
    }
}

// ---------------------------------------------------------------------------
// GEMM C[M,N] = A[M,K] * B^T[N,K]  (bf16 "NT"), BMx128 tile, BK=64, 4 waves.
// SPLITK>1: blockIdx.z selects K-slice; z=0 writes out(+bias+resid), z>0
// writes fp32 partial (reduced by addp_kernel).
// ---------------------------------------------------------------------------
enum { EPI_QKV3 = 0, EPI_BIAS_RES = 1, EPI_BIAS_GELU = 2 };

template <int EPI, int KDIM, int NDIM, int DBUF, int BM, int SPLITK>
__global__ __launch_bounds__(256) void gemm_nt(
    const unsigned short* __restrict__ A,
    const unsigned short* __restrict__ Bt,
    unsigned short* __restrict__ out0,
    unsigned short* __restrict__ out1,
    unsigned short* __restrict__ out2,
    float* __restrict__ outF,
    const float* __restrict__ bias,
    const float* __restrict__ resid,
    float* __restrict__ partial)
{
    constexpr int MF = BM / 32;        // m-fragments per wave
    constexpr int IA = BM / 32;        // A staging rounds
    constexpr int KLEN = KDIM / SPLITK;
    __shared__ __align__(16) unsigned short sA[DBUF + 1][BM * 64];
    __shared__ __align__(16) unsigned short sB[DBUF + 1][128 * 64];
    const int tid = threadIdx.x, lane = tid & 63, w = tid >> 6;
    const int bm = blockIdx.x * BM, bn = blockIdx.y * 128;
    const int kbeg = (SPLITK > 1) ? blockIdx.z * KLEN : 0;
    const int wm = (w >> 1) * (BM / 2), wn = (w & 1) * 64;
    const int rsel = lane & 15, g = lane >> 4;
    const int slot0 = w * 64 + lane;

    f32x4 acc[MF][4];
#pragma unroll
    for (int m = 0; m < MF; m++)
#pragma unroll
        for (int n = 0; n < 4; n++) acc[m][n] = (f32x4){0.f, 0.f, 0.f, 0.f};

    auto stage = [&](int buf, int k0) {
#pragma unroll
        for (int i = 0; i < IA; i++) {
            int slot = i * 256 + slot0;
            int row = slot >> 3, ch = slot & 7;
            int sc = ch ^ (row & 7);
            gload_lds16(&A[(size_t)(bm + row) * KDIM + k0 + sc * 8], &sA[buf][(i * 256 + w * 64) * 8]);
        }
#pragma unroll
        for (int i = 0; i < 4; i++) {
            int slot = i * 256 + slot0;
            int row = slot >> 3, ch = slot & 7;
            int sc = ch ^ (row & 7);
            gload_lds16(&Bt[(size_t)(bn + row) * KDIM + k0 + sc * 8], &sB[buf][(i * 256 + w * 64) * 8]);
        }
    };

    auto compute = [&](int buf) {
#pragma unroll
        for (int ks = 0; ks < 2; ks++) {
            short8 a[MF], b[4];
#pragma unroll
            for (int m = 0; m < MF; m++) a[m] = *swz_frag(sA[buf], wm + m * 16 + rsel, ks, g);
#pragma unroll
            for (int n = 0; n < 4; n++) b[n] = *swz_frag(sB[buf], wn + n * 16 + rsel, ks, g);
#pragma unroll
            for (int m = 0; m < MF; m++)
#pragma unroll
                for (int n = 0; n < 4; n++)
                    acc[m][n] = __builtin_amdgcn_mfma_f32_16x16x32_bf16(a[m], b[n], acc[m][n], 0, 0, 0);
        }
    };

    if constexpr (DBUF) {
        constexpr int NK = KLEN / 64;
        int cur = 0;
        stage(0, kbeg);
        __syncthreads();
        for (int kt = 0; kt < NK; ++kt) {
            if (kt + 1 < NK) stage(cur ^ 1, kbeg + (kt + 1) * 64);
            compute(cur);
            __syncthreads();
            cur ^= 1;
        }
    } else {
        for (int k0 = kbeg; k0 < kbeg + KLEN; k0 += 64) {
            __syncthreads();
            stage(0, k0);
            __syncthreads();
            compute(0);
        }
    }

    const int rq = g * 4;
#pragma unroll
    for (int m = 0; m < MF; m++)
#pragma unroll
        for (int n = 0; n < 4; n++)
#pragma unroll
            for (int j = 0; j < 4; j++) {
                int rg = bm + wm + m * 16 + rq + j;   // global row (B*T)
                int cg = bn + wn + n * 16 + rsel;     // global col
                float v = acc[m][n][j];
                if constexpr (EPI == EPI_QKV3) {
                    int which = cg >> 10, col = cg & 1023;
                    int h = col >> 6, dh = col & 63;
                    int bb = rg >> 11, t = rg & 2047;
                    if (which == 0)
                        out0[(((size_t)(bb * H_ + h)) * T_ + t) * DH_ + dh] = f2bf(v);
                    else if (which == 1)
                        out1[(((size_t)(bb * H_ + h)) * T_ + t) * DH_ + dh] = f2bf(v);
                    else
                        out2[(((size_t)(bb * H_ + h)) * DH_ + dh) * T_ + t] = f2bf(v);
                } else if constexpr (EPI == EPI_BIAS_RES) {
                    if (SPLITK > 1 && blockIdx.z != 0) {
                        partial[(size_t)rg * NDIM + cg] = v;
                    } else {
                        v += bias[cg] + resid[(size_t)rg * NDIM + cg];
                        outF[(size_t)rg * NDIM + cg] = v;
                    }
                } else {
                    // fast GELU (tanh form via exp2)
                    v += bias[cg];
                    float u = 0.7978845608028654f * (v + 0.044715f * v * v * v);
                    float e = exp2f(2.8853900817779268f * u);
                    v = v - v / (1.0f + e);
                    out0[(size_t)rg * NDIM + cg] = f2bf(v);
                }
            }
}

// ---------------------------------------------------------------------------
// Causal flash attention, swapped-QK^T formulation.
// S^T = mfma(K, Q): lane holds 16 S values (kv = sub*16+g*4+j) for ONE
// q = qbase + (lane&15) -> softmax stats are per-lane scalars (2 shfl_xor).
// PV as O^T = mfma(V^T, P): A-frag = sV rows (d), B-frag = P[q][kv] from a
// packed, XOR-swizzled per-wave LDS bounce (4x 8B writes, 2x b128 reads).
// XCD remap: bid&7 = XCD gets 4 heads; per-CU rounds qt {s,15-s,16+s,31-s}.
// ---------------------------------------------------------------------------
#define RESCALE_THR 8.0f

__global__ __launch_bounds__(256, 4) void attn_kernel(
    const unsigned short* __restrict__ q,
    const unsigned short* __restrict__ k,
    const unsigned short* __restrict__ vt,
    unsigned short* __restrict__ o)
{
    __shared__ __align__(16) unsigned short sK[2][64 * 64];   // 16 KB
    __shared__ __align__(16) unsigned short sV[2][64 * 64];   // 16 KB
    __shared__ __align__(16) unsigned short pl[4][1024];      //  8 KB ([16 q][64 kv]/wave)
    const int tid = threadIdx.x, lane = tid & 63, w = tid >> 6;

    // XCD-aware balanced remap
    const int x = blockIdx.x & 7, jb = blockIdx.x >> 3;
    const int bhl = jb & 3, ss = (jb >> 2) & 7, rr = jb >> 5;
    const int qt = (rr == 0) ? ss : (rr == 1) ? 15 - ss : (rr == 2) ? 16 + ss : 31 - ss;
    const int bh = x * 4 + bhl;

    const int qbase = qt * 64 + w * 16;
    const unsigned short* qp = q  + (size_t)bh * T_ * DH_;
    const unsigned short* kp = k  + (size_t)bh * T_ * DH_;
    const unsigned short* vp = vt + (size_t)bh * DH_ * T_;
    const int rsel = lane & 15, g = lane >> 4, koff = g * 8;
    const int slot0 = w * 64 + lane;
    const int swz = (rsel & 7) << 4;

    // Q fragments (B-operand of swapped QK^T): rows q = qbase + rsel
    short8 bq[2];
#pragma unroll
    for (int ks = 0; ks < 2; ks++)
        bq[ks] = *reinterpret_cast<const short8*>(
            &qp[(size_t)(qbase + rsel) * DH_ + ks * 32 + koff]);

    float mr = -INFINITY, lr = 0.f;
    f32x4 oacc[4];   // oacc[n][j] = O^T[d = n*16+g*4+j][q = qbase+rsel]
#pragma unroll
    for (int n = 0; n < 4; n++) oacc[n] = (f32x4){0.f, 0.f, 0.f, 0.f};

    const int nt = qt + 1;
    int cur = 0;

    auto stage = [&](int buf, int kv0) {
#pragma unroll
        for (int i = 0; i < 2; i++) {
            int slot = i * 256 + slot0;
            int row = slot >> 3, ch = slot & 7;
            int sc = ch ^ (row & 7);
            gload_lds16(&kp[(size_t)(kv0 + row) * DH_ + sc * 8], &sK[buf][(i * 256 + w * 64) * 8]);
            gload_lds16(&vp[(size_t)row * T_ + kv0 + sc * 8],    &sV[buf][(i * 256 + w * 64) * 8]);
        }
    };

    stage(0, 0);
    __syncthreads();

    unsigned short* plw = pl[w];
    for (int t = 0; t < nt; ++t) {
        const int kv0 = t * 64;
        if (t + 1 < nt) stage(cur ^ 1, (t + 1) * 64);
        // ---- QK^T swapped: S^T[kv][q] ----
        f32x4 s4[4];
#pragma unroll
        for (int sub = 0; sub < 4; sub++) {
            short8 ak0 = *swz_frag(sK[cur], sub * 16 + rsel, 0, g);
            short8 ak1 = *swz_frag(sK[cur], sub * 16 + rsel, 1, g);
            f32x4 t0 = (f32x4){0.f, 0.f, 0.f, 0.f};
            t0 = __builtin_amdgcn_mfma_f32_16x16x32_bf16(ak0, bq[0], t0, 0, 0, 0);
            t0 = __builtin_amdgcn_mfma_f32_16x16x32_bf16(ak1, bq[1], t0, 0, 0, 0);
            s4[sub] = t0;
        }
        // ---- causal mask: only the diagonal tile ----
        const int qg = qbase + rsel;
        if (t == nt - 1) {
#pragma unroll
            for (int sub = 0; sub < 4; sub++)
#pragma unroll
                for (int jj = 0; jj < 4; jj++) {
                    int kvg = kv0 + sub * 16 + g * 4 + jj;
                    if (kvg > qg) s4[sub][jj] = -1e30f;
                }
        }
        // ---- per-lane max over own 16, then 2 shfl across the q-group ----
        float mx = s4[0][0];
#pragma unroll
        for (int sub = 0; sub < 4; sub++)
#pragma unroll
            for (int jj = 0; jj < 4; jj++) mx = fmaxf(mx, s4[sub][jj]);
        mx = fmaxf(mx, __shfl_xor(mx, 16));
        mx = fmaxf(mx, __shfl_xor(mx, 32));
        // ---- defer-max (T13) ----
        if (__any(mx > mr + RESCALE_THR)) {
            float mn = fmaxf(mr, mx);
            float al = exp2f(mr - mn);
            mr = mn; lr *= al;
#pragma unroll
            for (int n = 0; n < 4; n++)
#pragma unroll
                for (int jj = 0; jj < 4; jj++) oacc[n][jj] *= al;
        }
        // ---- P = exp2(s - mr) -> packed swizzled bounce (4x 8B writes) ----
#pragma unroll
        for (int sub = 0; sub < 4; sub++) {
            float p0 = exp2f(s4[sub][0] - mr);
            float p1 = exp2f(s4[sub][1] - mr);
            float p2 = exp2f(s4[sub][2] - mr);
            float p3 = exp2f(s4[sub][3] - mr);
            lr += (p0 + p1) + (p2 + p3);
            uint2 pk;
            pk.x = f2bf_trunc(p0) | (f2bf_trunc(p1) << 16);
            pk.y = f2bf_trunc(p2) | (f2bf_trunc(p3) << 16);
            int byte = rsel * 128 + ((sub * 32 + g * 8) ^ swz);
            *reinterpret_cast<uint2*>(reinterpret_cast<char*>(plw) + byte) = pk;
        }
        // ---- PV: O^T = V^T x P  (A = sV rows d, B = P rows q) ----
#pragma unroll
        for (int ks = 0; ks < 2; ks++) {
            int rbyte = rsel * 128 + ((ks * 64 + g * 16) ^ swz);
            short8 bp = *reinterpret_cast<const short8*>(
                reinterpret_cast<const char*>(plw) + rbyte);
#pragma unroll
            for (int n = 0; n < 4; n++) {
                short8 av = *swz_frag(sV[cur], n * 16 + rsel, ks, g);
                oacc[n] = __builtin_amdgcn_mfma_f32_16x16x32_bf16(av, bp, oacc[n], 0, 0, 0);
            }
        }
        __syncthreads();
        cur ^= 1;
    }

    // ---- finish: scalar l reduce (2 shfl), packed 8B output stores ----
    lr += __shfl_xor(lr, 16);
    lr += __shfl_xor(lr, 32);
    float inv = 1.0f / lr;
    const int bb = bh >> 4, h = bh & 15;
    const int rg = qbase + rsel;
    unsigned short* ob = o + ((size_t)(bb * T_ + rg)) * D_ + h * DH_ + g * 4;
#pragma unroll
    for (int n = 0; n < 4; n++) {
        uint2 pk;
        pk.x = (unsigned)f2bf(oacc[n][0] * inv) | ((unsigned)f2bf(oacc[n][1] * inv) << 16);
        pk.y = (unsigned)f2bf(oacc[n][2] * inv) | ((unsigned)f2bf(oacc[n][3] * inv) << 16);
        *reinterpret_cast<uint2*>(ob + n * 16) = pk;
    }
}

// ---------------------------------------------------------------------------
// Launch sequence
// ---------------------------------------------------------------------------
extern "C" void kernel_launch(void* const* d_in, const int* in_sizes, int n_in,
                              void* d_out, int out_size, void* d_ws, size_t ws_size,
                              hipStream_t stream)
{
    const float* x    = (const float*)d_in[0];
    const float* wq   = (const float*)d_in[1];
    const float* wk   = (const float*)d_in[2];
    const float* wv   = (const float*)d_in[3];
    const float* wo   = (const float*)d_in[4];
    const float* bo   = (const float*)d_in[5];
    const float* w1   = (const float*)d_in[6];
    const float* b1   = (const float*)d_in[7];
    const float* w2   = (const float*)d_in[8];
    const float* b2   = (const float*)d_in[9];
    const float* ln1s = (const float*)d_in[10];
    const float* ln1b = (const float*)d_in[11];
    const float* ln2s = (const float*)d_in[12];
    const float* ln2b = (const float*)d_in[13];
    float* out = (float*)d_out;

    char* ws = (char*)d_ws;
    unsigned short* wqkv_t = (unsigned short*)ws;                     // [3072][1024]
    unsigned short* wo_t   = wqkv_t + (size_t)3072 * 1024;            // [1024][1024]
    unsigned short* w1_t   = wo_t   + (size_t)1024 * 1024;            // [4096][1024]
    unsigned short* w2_t   = w1_t   + (size_t)4096 * 1024;            // [1024][4096]
    unsigned short* hbuf   = w2_t   + (size_t)1024 * 4096;            // [4096][1024]
    unsigned short* qb     = hbuf   + (size_t)4096 * 1024;            // (B,H,T,DH)
    unsigned short* kb     = qb     + (size_t)32 * 2048 * 64;
    unsigned short* vtb    = kb     + (size_t)32 * 2048 * 64;         // (B,H,DH,T)
    unsigned short* ao     = vtb    + (size_t)32 * 64 * 2048;         // (B,T,D)
    unsigned short* f1     = qb;    // reuse q|k|vt|ao span after attention+WO
    // split-K partial: overlays wqkv_t+wo_t+w1_t (all dead by FF2) = 16.78 MB
    float* fpart = (float*)ws;

    // weight converts (wq folded with 0.125 * log2(e) for exp2-domain softmax)
    cvt_t_kernel<<<dim3(16, 16), 256, 0, stream>>>(wq, wqkv_t,                   1024, 1024, 0.180336880111120425f);
    cvt_t_kernel<<<dim3(16, 16), 256, 0, stream>>>(wk, wqkv_t + 1024 * 1024,     1024, 1024, 1.f);
    cvt_t_kernel<<<dim3(16, 16), 256, 0, stream>>>(wv, wqkv_t + 2 * 1024 * 1024, 1024, 1024, 1.f);
    cvt_t_kernel<<<dim3(16, 16), 256, 0, stream>>>(wo, wo_t, 1024, 1024, 1.f);
    cvt_t_kernel<<<dim3(16, 64), 256, 0, stream>>>(w1, w1_t, 1024, 4096, 1.f);
    cvt_t_kernel<<<dim3(64, 16), 256, 0, stream>>>(w2, w2_t, 4096, 1024, 1.f);

    // attention sublayer
    ln_kernel<<<M_, 256, 0, stream>>>(x, ln1s, ln1b, hbuf);
    gemm_nt<EPI_QKV3, 1024, 3072, 0, 128, 1><<<dim3(32, 24), 256, 0, stream>>>(
        hbuf, wqkv_t, qb, kb, vtb, nullptr, nullptr, nullptr, nullptr);
    attn_kernel<<<1024, 256, 0, stream>>>(qb, kb, vtb, ao);
    gemm_nt<EPI_BIAS_RES, 1024, 1024, 1, 64, 1><<<dim3(64, 8), 256, 0, stream>>>(
        ao, wo_t, nullptr, nullptr, nullptr, out, bo, x, nullptr);   // out = x2
    // feed-forward sublayer
    ln_kernel<<<M_, 256, 0, stream>>>(out, ln2s, ln2b, hbuf);
    gemm_nt<EPI_BIAS_GELU, 1024, 4096, 0, 128, 1><<<dim3(32, 32), 256, 0, stream>>>(
        hbuf, w1_t, f1, nullptr, nullptr, nullptr, b1, nullptr, nullptr);
    gemm_nt<EPI_BIAS_RES, 4096, 1024, 0, 64, 2><<<dim3(64, 8, 2), 256, 0, stream>>>(
        f1, w2_t, nullptr, nullptr, nullptr, out, b2, out, fpart);   // z=0: out, z=1: fpart
    addp_kernel<<<2048, 256, 0, stream>>>(out, fpart);               // out += fpart
}